// Round 13
// baseline (323.558 us; speedup 1.0000x reference)
//
#include <hip/hip_runtime.h>
#include <hip/hip_bf16.h>
#include <hip/hip_fp16.h>
#include <math.h>

#define D    1024
#define H    16
#define DH   64
#define S    1024
#define M    1024
#define B    2
#define J    2048          // M + S
#define SCALE 0.125f       // 1/sqrt(64)
#define SCALE_L2E 0.18033688f   // SCALE * log2(e): softmax uses bare exp2

typedef __attribute__((ext_vector_type(8))) short        bf16x8;
typedef __attribute__((ext_vector_type(4))) short        s16x4;
typedef __attribute__((ext_vector_type(8))) _Float16     h16x8;
typedef __attribute__((ext_vector_type(4))) _Float16     h16x4;
typedef __attribute__((ext_vector_type(8))) unsigned short us8;
typedef __attribute__((ext_vector_type(4))) unsigned short us4;
typedef __attribute__((ext_vector_type(4))) float        f32x4;

__device__ __forceinline__ short f2bs(float f) {
    __hip_bfloat16 t = __float2bfloat16(f);
    short r; __builtin_memcpy(&r, &t, 2); return r;
}
// fast bf16 pack (round-half-up); inputs finite non-negative (probs)
__device__ __forceinline__ unsigned short f2bf_fast(float f) {
    unsigned int u; __builtin_memcpy(&u, &f, 4);
    return (unsigned short)((u + 0x8000u) >> 16);
}

// async global->LDS, 16 bytes per lane
__device__ __forceinline__ void g2l16(const short* g, short* l) {
    __builtin_amdgcn_global_load_lds(
        (const __attribute__((address_space(1))) unsigned int*)g,
        (__attribute__((address_space(3))) unsigned int*)l, 16, 0, 0);
}

// ---------------------------------------------------------------------------
// prep: blocks [0,6144)  fp32->bf16 flat convert (mem||x -> a_bf, pemb -> p_bf)
//       blocks [6144,7424) 64x64 weight transpose+convert W[k][n] -> Wt[n][k]
// ---------------------------------------------------------------------------
__global__ __launch_bounds__(256)
void prep(const float* __restrict__ mem, const float* __restrict__ x,
          const float* __restrict__ pemb,
          const float* __restrict__ Wkv, const float* __restrict__ Wq,
          const float* __restrict__ Wpos, const float* __restrict__ Wout,
          short* __restrict__ a_bf, short* __restrict__ p_bf,
          short* __restrict__ wkvt, short* __restrict__ wqt,
          short* __restrict__ wpt,  short* __restrict__ wot)
{
    __shared__ float t[64][65];
    int blk = blockIdx.x;
    const int tid = threadIdx.x;
    if (blk < 6144) {
        const int idx = (blk * 256 + tid) * 4;
        const int TWO_M = 2 * 1024 * 1024;
        float4 v; short* dst;
        if (idx < TWO_M)          { v = *(const float4*)(mem  + idx);           dst = a_bf + idx; }
        else if (idx < 2 * TWO_M) { v = *(const float4*)(x    + idx - TWO_M);   dst = a_bf + idx; }
        else                      { v = *(const float4*)(pemb + idx - 2*TWO_M); dst = p_bf + idx - 2*TWO_M; }
        s16x4 o = { f2bs(v.x), f2bs(v.y), f2bs(v.z), f2bs(v.w) };
        *(s16x4*)dst = o;
        return;
    }
    blk -= 6144;
    const float* src; short* dst; int N, t0;
    if (blk < 512)       { src = Wkv;  dst = wkvt; N = 2048; t0 = blk; }
    else if (blk < 768)  { src = Wq;   dst = wqt;  N = 1024; t0 = blk - 512; }
    else if (blk < 1024) { src = Wpos; dst = wpt;  N = 1024; t0 = blk - 768; }
    else                 { src = Wout; dst = wot;  N = 1024; t0 = blk - 1024; }
    const int ntn = N >> 6;
    const int k0 = (t0 / ntn) * 64, n0 = (t0 % ntn) * 64;
    #pragma unroll
    for (int e = tid; e < 4096; e += 256) {
        int r = e >> 6, c = e & 63;
        t[r][c] = src[(size_t)(k0 + r) * N + n0 + c];
    }
    __syncthreads();
    #pragma unroll
    for (int e = tid; e < 4096; e += 256) {
        int nr = e >> 6, kc = e & 63;
        dst[(size_t)(n0 + nr) * 1024 + k0 + kc] = f2bs(t[kc][nr]);
    }
}

// ---------------------------------------------------------------------------
// Shared MFMA GEMM core: BM=BN=128, BK=64, 256 thr, K=1024.
// ---------------------------------------------------------------------------
__device__ __forceinline__ void gemm_core(const short* __restrict__ A,
                                          const short* __restrict__ Bt,
                                          short* As, short* Bs,
                                          int bm0, int bn0, int tid,
                                          f32x4 acc[4][4])
{
    const int w    = tid >> 6;
    const int wy   = w >> 1, wx = w & 1;
    const int lane = tid & 63;
    const int lm   = lane & 15;
    const int lq   = lane >> 4;

    for (int k0 = 0; k0 < 1024; k0 += 64) {
        const short* Ab = A  + (size_t)bm0 * 1024 + k0;
        const short* Bb = Bt + (size_t)bn0 * 1024 + k0;
        #pragma unroll
        for (int t = 0; t < 4; ++t) {
            int s = t * 256 + tid;
            int r = s >> 3, c = s & 7;
            int cg = c ^ (r & 7);
            g2l16(Ab + r * 1024 + cg * 8, As + s * 8);
            g2l16(Bb + r * 1024 + cg * 8, Bs + s * 8);
        }
        __syncthreads();
        #pragma unroll
        for (int kk = 0; kk < 2; ++kk) {
            bf16x8 af[4], bg[4];
            #pragma unroll
            for (int r4 = 0; r4 < 4; ++r4) {
                int ar = wy * 64 + r4 * 16 + lm;
                int kc = kk * 4 + lq;
                af[r4] = *(const bf16x8*)(As + ((ar << 3) + (kc ^ (ar & 7))) * 8);
            }
            #pragma unroll
            for (int c4 = 0; c4 < 4; ++c4) {
                int br = wx * 64 + c4 * 16 + lm;
                int kc = kk * 4 + lq;
                bg[c4] = *(const bf16x8*)(Bs + ((br << 3) + (kc ^ (br & 7))) * 8);
            }
            #pragma unroll
            for (int r4 = 0; r4 < 4; ++r4)
                #pragma unroll
                for (int c4 = 0; c4 < 4; ++c4)
                    acc[r4][c4] = __builtin_amdgcn_mfma_f32_16x16x32_bf16(
                        af[r4], bg[c4], acc[r4][c4], 0, 0, 0);
        }
        __syncthreads();
    }
}

// ---------------------------------------------------------------------------
// Fused kv/q/r projections. qu/qv scaled by SCALE*log2(e) (bare exp2 attn).
// R18 XCD-aware block remap (bijective: 768 = 8 x 96).
// ---------------------------------------------------------------------------
__global__ __launch_bounds__(256)
void proj_fused(const short* __restrict__ a_bf, const short* __restrict__ p_bf,
                const short* __restrict__ wkvt, const short* __restrict__ wqt,
                const short* __restrict__ wpt,
                short* __restrict__ k_bf, short* __restrict__ vt_bf,
                short* __restrict__ qu_bf, short* __restrict__ qv_bf,
                short* __restrict__ r_bf,
                const float* __restrict__ uvec, const float* __restrict__ vvec)
{
    __shared__ __align__(16) short As[128 * 64];
    __shared__ __align__(16) short Bs[128 * 64];

    // XCD remap: HW sends original id L to XCD L&7; logical id below makes
    // XCD x execute the contiguous logical range [x*96, (x+1)*96).
    int blk = (blockIdx.x & 7) * 96 + (blockIdx.x >> 3);

    int mode, bx, by;
    const short *A, *Bt;
    if (blk < 512)      { bx = blk & 15; by = blk >> 4;
                          if (bx >= 8) { mode = 4; A = wkvt; Bt = a_bf; }   // swapped V
                          else         { mode = 0; A = a_bf; Bt = wkvt; } }
    else if (blk < 640) { int b2 = blk - 512; mode = 1; bx = b2 & 7; by = b2 >> 3;
                          A = a_bf + (size_t)2048 * 1024; Bt = wqt; }
    else                { int b3 = blk - 640; mode = 2; bx = b3 & 7; by = b3 >> 3;
                          A = p_bf; Bt = wpt; }
    const int bn0 = (mode == 4) ? by * 128 : bx * 128;
    const int bm0 = (mode == 4) ? bx * 128 : by * 128;
    const int tid = threadIdx.x;
    const int w = tid >> 6, wy = w >> 1, wx = w & 1;
    const int lane = tid & 63, lm = lane & 15, lq = lane >> 4;

    f32x4 acc[4][4];
    #pragma unroll
    for (int r = 0; r < 4; ++r)
        #pragma unroll
        for (int c = 0; c < 4; ++c) acc[r][c] = (f32x4){0.f, 0.f, 0.f, 0.f};

    gemm_core(A, Bt, As, Bs, bm0, bn0, tid, acc);

    #pragma unroll
    for (int r4 = 0; r4 < 4; ++r4) {
        #pragma unroll
        for (int c4 = 0; c4 < 4; ++c4) {
            const int n = bn0 + wx * 64 + c4 * 16 + lm;
            float ubias = 0.f, vbias = 0.f;
            if (mode == 1) { ubias = uvec[n]; vbias = vvec[n]; }
            #pragma unroll
            for (int reg = 0; reg < 4; ++reg) {
                const int m = bm0 + wy * 64 + r4 * 16 + lq * 4 + reg;
                const float val = acc[r4][c4][reg];
                if (mode == 0) {
                    int j = m >> 1, b = m & 1;
                    int h = n >> 6, d = n & 63;
                    k_bf[(((size_t)b * H + h) * J + j) * DH + d] = f2bs(val);
                } else if (mode == 4) {
                    int n2 = m - 1024, h = n2 >> 6, d = n2 & 63;
                    int j = n >> 1, b = n & 1;
                    vt_bf[(((size_t)b * H + h) * DH + d) * J + j] = f2bs(val);
                } else if (mode == 1) {
                    int i = m >> 1, b = m & 1;
                    int h = n >> 6, d = n & 63;
                    size_t o = (((size_t)b * H + h) * S + i) * DH + d;
                    qu_bf[o] = f2bs((val + ubias) * SCALE_L2E);
                    qv_bf[o] = f2bs((val + vbias) * SCALE_L2E);
                } else {
                    int h = n >> 6, d = n & 63;
                    r_bf[((size_t)h * J + m) * DH + d] = f2bs(val);
                }
            }
        }
    }
}

// ---------------------------------------------------------------------------
// Output projection: M=2048, N=1024, fp32 out. BM=64, BN=128, 256 blocks,
// XCD-contiguous logical order.
// ---------------------------------------------------------------------------
__global__ __launch_bounds__(256)
void gemm_out(const short* __restrict__ A, const short* __restrict__ Bt,
              float* __restrict__ out)
{
    __shared__ __align__(16) short As[64 * 64];    // 8 KB
    __shared__ __align__(16) short Bs[128 * 64];   // 16 KB
    const int lb = (blockIdx.x & 7) * 32 + (blockIdx.x >> 3);  // XCD-contig
    const int bn0 = (lb & 7) * 128, bm0 = (lb >> 3) * 64;
    const int tid = threadIdx.x;
    const int w = tid >> 6;                 // 0..3 = column-split wave index
    const int lane = tid & 63, lm = lane & 15, lq = lane >> 4;

    f32x4 acc[4][2];
    #pragma unroll
    for (int r = 0; r < 4; ++r)
        #pragma unroll
        for (int c = 0; c < 2; ++c) acc[r][c] = (f32x4){0.f, 0.f, 0.f, 0.f};

    for (int k0 = 0; k0 < 1024; k0 += 64) {
        const short* Ab = A  + (size_t)bm0 * 1024 + k0;
        const short* Bb = Bt + (size_t)bn0 * 1024 + k0;
        #pragma unroll
        for (int t = 0; t < 2; ++t) {       // A: 64 rows
            int s = t * 256 + tid;
            int r = s >> 3, c = s & 7;
            int cg = c ^ (r & 7);
            g2l16(Ab + r * 1024 + cg * 8, As + s * 8);
        }
        #pragma unroll
        for (int t = 0; t < 4; ++t) {       // B: 128 rows
            int s = t * 256 + tid;
            int r = s >> 3, c = s & 7;
            int cg = c ^ (r & 7);
            g2l16(Bb + r * 1024 + cg * 8, Bs + s * 8);
        }
        __syncthreads();
        #pragma unroll
        for (int kk = 0; kk < 2; ++kk) {
            bf16x8 af[4], bg[2];
            #pragma unroll
            for (int r4 = 0; r4 < 4; ++r4) {
                int ar = r4 * 16 + lm;
                int kc = kk * 4 + lq;
                af[r4] = *(const bf16x8*)(As + ((ar << 3) + (kc ^ (ar & 7))) * 8);
            }
            #pragma unroll
            for (int c4 = 0; c4 < 2; ++c4) {
                int br = w * 32 + c4 * 16 + lm;
                int kc = kk * 4 + lq;
                bg[c4] = *(const bf16x8*)(Bs + ((br << 3) + (kc ^ (br & 7))) * 8);
            }
            #pragma unroll
            for (int r4 = 0; r4 < 4; ++r4)
                #pragma unroll
                for (int c4 = 0; c4 < 2; ++c4)
                    acc[r4][c4] = __builtin_amdgcn_mfma_f32_16x16x32_bf16(
                        af[r4], bg[c4], acc[r4][c4], 0, 0, 0);
        }
        __syncthreads();
    }

    #pragma unroll
    for (int r4 = 0; r4 < 4; ++r4)
        #pragma unroll
        for (int c4 = 0; c4 < 2; ++c4) {
            const int n = bn0 + w * 32 + c4 * 16 + lm;
            #pragma unroll
            for (int reg = 0; reg < 4; ++reg) {
                const int m = bm0 + r4 * 16 + lq * 4 + reg;
                out[(size_t)m * 1024 + n] = acc[r4][c4][reg];
            }
        }
}

// ---------------------------------------------------------------------------
// MFMA attention. R22 = R21 (fused jh loop) with the persistent accumulator
// halved so two blocks co-reside. R21 diagnosis: reported VGPR excludes MFMA
// accumulators; 104 arch + 32 acc (pa+pb) = 136 > 128 -> 1 block/CU (22%).
// Fix: PV wave split by (d-slice, ROW-HALF) instead of (d-slice, j-quarter):
// each wave keeps only pa0..3 (16 acc) and covers its 16 rows over ALL
// 1024 j (8 chunks x 4 MFMA = same 32 MFMA). V loads double (L2-hot, ~free).
// Bonus: each (row,d) owned by one wave -> epilogue scF LDS round-trip and
// one barrier DELETED (direct o_bf write after rtot normalize).
// __launch_bounds__(512,4) pins the unified-file target at 128 (est demand
// ~110-120 -> no/tiny spill; watch WRITE_SIZE). Fused-1-block already beat
// split-2-block (117.6 vs 121.6); this measures fused + 2-resident.
// ---------------------------------------------------------------------------
__device__ __forceinline__ int sidx(int m, int c) {   // m in [0,32), c in [0,1024)
    return (m << 10) + (c ^ (m << 3));
}

__global__ __launch_bounds__(512, 4)
void attn_mfma(const short* __restrict__ qu_bf, const short* __restrict__ qv_bf,
               const short* __restrict__ k_bf,  const short* __restrict__ vt_bf,
               const short* __restrict__ r_bf,
               short* __restrict__ o_bf)
{
    __shared__ unsigned short sc[32 * 1024];   // 64 KB
    __shared__ float wsum[16][2][8];           // per-wave row partials
    __shared__ float rtot[32];                 // final inverse row sums
    __half* sch = (__half*)sc;

    // XCD-aware decode: L&7 = XCD; each XCD owns bh in [4*xcd, 4*xcd+4).
    const int L   = blockIdx.x;
    const int xcd = L & 7;
    const int pp  = L >> 3;                    // 0..127
    const int bh  = (xcd << 2) + (pp >> 5);    // 4 streams per XCD
    const int it  = pp & 31;

    const int i0  = it * 32;
    const int h   = bh & (H - 1);
    const int tid = threadIdx.x;
    const int w    = tid >> 6;       // 0..7
    const int lane = tid & 63;
    const int lm   = lane & 15;
    const int lq   = lane >> 4;
    const int dslice = w & 3, rh = w >> 2, mrp = rh * 16;

    const short* rbase = r_bf + (size_t)h * J * DH;
    const short* kbase = k_bf + (size_t)bh * J * DH;

    float sum0 = 0.f, sum1 = 0.f;
    f32x4 pa0 = {0.f,0.f,0.f,0.f}, pa1 = {0.f,0.f,0.f,0.f};
    f32x4 pa2 = {0.f,0.f,0.f,0.f}, pa3 = {0.f,0.f,0.f,0.f};

    #pragma unroll 1
    for (int jh = 0; jh < 2; ++jh) {
        const int cbeg = jh << 10, cend = cbeg + 1024;
        if (jh) __syncthreads();   // prev PV score reads done before overwrite

        // ---- Qv / Qw fragments (per iteration; short live ranges) ----
        const short* qvp0 = qv_bf + ((size_t)(bh * S + i0 + lm)) * DH + lq * 8;
        const short* qvp1 = qvp0 + 16 * DH;
        bf16x8 av00 = *(const bf16x8*)qvp0, av01 = *(const bf16x8*)(qvp0 + 32);
        bf16x8 av10 = *(const bf16x8*)qvp1, av11 = *(const bf16x8*)(qvp1 + 32);
        int r1a = i0 + 1 + lm;  if (r1a > S - 1) r1a = S - 1;   // clamped rows masked
        int r1b = i0 + 17 + lm; if (r1b > S - 1) r1b = S - 1;
        const short* qwp0 = qv_bf + ((size_t)(bh * S + r1a)) * DH + lq * 8;
        const short* qwp1 = qv_bf + ((size_t)(bh * S + r1b)) * DH + lq * 8;
        bf16x8 aw00 = *(const bf16x8*)qwp0, aw01 = *(const bf16x8*)(qwp0 + 32);
        bf16x8 aw10 = *(const bf16x8*)qwp1, aw11 = *(const bf16x8*)(qwp1 + 32);

        // ---- zero the pos hole column: row m, col i0+m+1025 (if in window) ----
        if (tid < 32) {
            int hole = i0 + tid + 1025;
            if (hole >= cbeg && hole < cend) sc[sidx(tid, hole - cbeg)] = 0;
        }

        // ---- pos main: col = i0 + 16t + lm + m - 1023; direct loads ----
        {
            int tmp = cbeg + 977 - i0;
            int tlo = tmp > 0 ? ((tmp + 15) >> 4) : 0;
            int thi = (cend + 1022 - i0) >> 4; if (thi > 127) thi = 127;
            for (int t = tlo + w; t <= thi; t += 8) {
                const short* rp = rbase + (size_t)(t * 16 + lm) * DH + lq * 8;
                bf16x8 b0 = *(const bf16x8*)rp, b1 = *(const bf16x8*)(rp + 32);
                f32x4 c0 = {0.f,0.f,0.f,0.f}, c1 = {0.f,0.f,0.f,0.f};
                __builtin_amdgcn_s_setprio(1);
                c0 = __builtin_amdgcn_mfma_f32_16x16x32_bf16(av00, b0, c0, 0, 0, 0);
                c1 = __builtin_amdgcn_mfma_f32_16x16x32_bf16(av10, b0, c1, 0, 0, 0);
                c0 = __builtin_amdgcn_mfma_f32_16x16x32_bf16(av01, b1, c0, 0, 0, 0);
                c1 = __builtin_amdgcn_mfma_f32_16x16x32_bf16(av11, b1, c1, 0, 0, 0);
                __builtin_amdgcn_s_setprio(0);
                int cb = i0 + t * 16 + lm - 1023 - cbeg;     // local col for m=0
                int base = i0 + 16 * t - 1023;               // scalar col_min
                if (base >= cbeg && base + 46 < cend) {
                    #pragma unroll
                    for (int r = 0; r < 4; ++r) {
                        int m0 = lq * 4 + r, m1 = m0 + 16;
                        sch[sidx(m0, cb + m0)] = __float2half(c0[r]);
                        sch[sidx(m1, cb + m1)] = __float2half(c1[r]);
                    }
                } else {
                    #pragma unroll
                    for (int r = 0; r < 4; ++r) {
                        int m0 = lq * 4 + r, m1 = m0 + 16;
                        int cA = cb + m0, cB = cb + m1;
                        if (cA >= 0 && cA < 1024) sch[sidx(m0, cA)] = __float2half(c0[r]);
                        if (cB >= 0 && cB < 1024) sch[sidx(m1, cB)] = __float2half(c1[r]);
                    }
                }
            }
        }

        // ---- pos wrap: col = i0 + 16t + lm + m + 1026, rows Qv[i+1] ----
        {
            int tmpw = cbeg - 1072 - i0;
            int tlw = tmpw > 0 ? ((tmpw + 15) >> 4) : 0;
            int thw = (cend - 1027 - i0) >> 4; if (thw > 127) thw = 127;
            for (int t = tlw + w; t <= thw; t += 8) {
                const short* rp = rbase + (size_t)(t * 16 + lm) * DH + lq * 8;
                bf16x8 b0 = *(const bf16x8*)rp, b1 = *(const bf16x8*)(rp + 32);
                f32x4 c0 = {0.f,0.f,0.f,0.f}, c1 = {0.f,0.f,0.f,0.f};
                __builtin_amdgcn_s_setprio(1);
                c0 = __builtin_amdgcn_mfma_f32_16x16x32_bf16(aw00, b0, c0, 0, 0, 0);
                c1 = __builtin_amdgcn_mfma_f32_16x16x32_bf16(aw10, b0, c1, 0, 0, 0);
                c0 = __builtin_amdgcn_mfma_f32_16x16x32_bf16(aw01, b1, c0, 0, 0, 0);
                c1 = __builtin_amdgcn_mfma_f32_16x16x32_bf16(aw11, b1, c1, 0, 0, 0);
                __builtin_amdgcn_s_setprio(0);
                int cb = i0 + t * 16 + lm + 1026 - cbeg;
                int base = i0 + 16 * t + 1026;
                if (base >= cbeg && base + 46 < cend) {
                    #pragma unroll
                    for (int r = 0; r < 4; ++r) {
                        int m0 = lq * 4 + r, m1 = m0 + 16;
                        sch[sidx(m0, cb + m0)] = __float2half(c0[r]);
                        sch[sidx(m1, cb + m1)] = __float2half(c1[r]);
                    }
                } else {
                    #pragma unroll
                    for (int r = 0; r < 4; ++r) {
                        int m0 = lq * 4 + r, m1 = m0 + 16;
                        int cA = cb + m0, cB = cb + m1;
                        if (cA >= 0 && cA < 1024) sch[sidx(m0, cA)] = __float2half(c0[r]);
                        if (cB >= 0 && cB < 1024) sch[sidx(m1, cB)] = __float2half(c1[r]);
                    }
                }
            }
        }

        // ---- prefetch first content K-tile before the barrier ----
        bf16x8 kb0, kb1;
        {
            int t0 = jh * 64 + w + 8 * (it & 7);
            const short* kp0 = kbase + (size_t)(t0 * 16 + lm) * DH + lq * 8;
            kb0 = *(const bf16x8*)kp0; kb1 = *(const bf16x8*)(kp0 + 32);
        }
        __syncthreads();

        // ---- Qu fragments ----
        const short* qup0 = qu_bf + ((size_t)(bh * S + i0 + lm)) * DH + lq * 8;
        const short* qup1 = qup0 + 16 * DH;
        bf16x8 au00 = *(const bf16x8*)qup0, au01 = *(const bf16x8*)(qup0 + 32);
        bf16x8 au10 = *(const bf16x8*)qup1, au11 = *(const bf16x8*)(qup1 + 32);

        // ---- content + softmax FUSED; depth-1 rolling K prefetch ----
        #pragma unroll 1
        for (int g = 0; g < 8; ++g) {
            bf16x8 nb0, nb1;
            if (g + 1 < 8) {
                int u = jh * 64 + w + 8 * ((g + 1 + it) & 7);
                const short* np = kbase + (size_t)(u * 16 + lm) * DH + lq * 8;
                nb0 = *(const bf16x8*)np; nb1 = *(const bf16x8*)(np + 32);
            }
            int t = jh * 64 + w + 8 * ((g + it) & 7);
            int lc = t * 16 - cbeg;                  // 16-aligned local col base
            int aA = sidx(lm,      lc + lq * 4);     // 4 consecutive u16, 8B-aligned
            int aB = sidx(lm + 16, lc + lq * 4);
            h16x4 hA = *(const h16x4*)(sc + aA);
            h16x4 hB = *(const h16x4*)(sc + aB);
            f32x4 c0, c1;
            #pragma unroll
            for (int r = 0; r < 4; ++r) { c0[r] = (float)hA[r]; c1[r] = (float)hB[r]; }
            __builtin_amdgcn_s_setprio(1);
            c0 = __builtin_amdgcn_mfma_f32_16x16x32_bf16(kb0, au00, c0, 0, 0, 0);
            c1 = __builtin_amdgcn_mfma_f32_16x16x32_bf16(kb0, au10, c1, 0, 0, 0);
            c0 = __builtin_amdgcn_mfma_f32_16x16x32_bf16(kb1, au01, c0, 0, 0, 0);
            c1 = __builtin_amdgcn_mfma_f32_16x16x32_bf16(kb1, au11, c1, 0, 0, 0);
            __builtin_amdgcn_s_setprio(0);
            us4 oA, oB;
            #pragma unroll
            for (int r = 0; r < 4; ++r) {
                float e0 = __builtin_amdgcn_exp2f(c0[r]);
                float e1 = __builtin_amdgcn_exp2f(c1[r]);
                sum0 += e0; sum1 += e1;
                oA[r] = f2bf_fast(e0);
                oB[r] = f2bf_fast(e1);
            }
            *(us4*)(sc + aA) = oA;
            *(us4*)(sc + aB) = oB;
            kb0 = nb0; kb1 = nb1;
        }

        // ---- prefetch first PV V-chunk before the barrier ----
        const short* vtb = vt_bf + ((size_t)bh * DH + dslice * 16 + lm) * J + cbeg;
        bf16x8 cv0, cv1, cv2, cv3;
        {
            int j0 = (it & 7) * 128;
            cv0 = *(const bf16x8*)(vtb + j0 +  0 + lq * 8);
            cv1 = *(const bf16x8*)(vtb + j0 + 32 + lq * 8);
            cv2 = *(const bf16x8*)(vtb + j0 + 64 + lq * 8);
            cv3 = *(const bf16x8*)(vtb + j0 + 96 + lq * 8);
        }
        __syncthreads();

        // ---- PV: wave -> (d-slice, row-half); 8 x 128 j per jh ----
        #pragma unroll 1
        for (int jo = 0; jo < 8; ++jo) {
            bf16x8 nv0, nv1, nv2, nv3;
            if (jo < 7) {
                int jn = ((jo + 1 + it) & 7) * 128;
                nv0 = *(const bf16x8*)(vtb + jn +  0 + lq * 8);
                nv1 = *(const bf16x8*)(vtb + jn + 32 + lq * 8);
                nv2 = *(const bf16x8*)(vtb + jn + 64 + lq * 8);
                nv3 = *(const bf16x8*)(vtb + jn + 96 + lq * 8);
            }
            int jc = ((jo + it) & 7) * 128;
            bf16x8 a0 = *(const bf16x8*)(sc + sidx(mrp + lm, jc +  0 + lq * 8));
            bf16x8 a1 = *(const bf16x8*)(sc + sidx(mrp + lm, jc + 32 + lq * 8));
            bf16x8 a2 = *(const bf16x8*)(sc + sidx(mrp + lm, jc + 64 + lq * 8));
            bf16x8 a3 = *(const bf16x8*)(sc + sidx(mrp + lm, jc + 96 + lq * 8));
            __builtin_amdgcn_s_setprio(1);
            pa0 = __builtin_amdgcn_mfma_f32_16x16x32_bf16(a0, cv0, pa0, 0, 0, 0);
            pa1 = __builtin_amdgcn_mfma_f32_16x16x32_bf16(a1, cv1, pa1, 0, 0, 0);
            pa2 = __builtin_amdgcn_mfma_f32_16x16x32_bf16(a2, cv2, pa2, 0, 0, 0);
            pa3 = __builtin_amdgcn_mfma_f32_16x16x32_bf16(a3, cv3, pa3, 0, 0, 0);
            __builtin_amdgcn_s_setprio(0);
            if (jo < 7) { cv0 = nv0; cv1 = nv1; cv2 = nv2; cv3 = nv3; }
        }
    }

    // ---- epilogue: row sums -> rtot; direct normalized o_bf write ----
    sum0 += __shfl_xor(sum0, 16); sum0 += __shfl_xor(sum0, 32);
    sum1 += __shfl_xor(sum1, 16); sum1 += __shfl_xor(sum1, 32);
    if (lane < 16) { wsum[lane][0][w] = sum0; wsum[lane][1][w] = sum1; }
    __syncthreads();
    if (tid < 32) {
        float s = 0.f;
        #pragma unroll
        for (int ww = 0; ww < 8; ++ww) s += wsum[tid & 15][tid >> 4][ww];
        rtot[tid] = 1.0f / s;
    }
    __syncthreads();

    const int bb = bh >> 4;
    #pragma unroll
    for (int r = 0; r < 4; ++r) {
        int m = mrp + lq * 4 + r;            // this wave's rows
        float val = (pa0[r] + pa1[r] + pa2[r] + pa3[r]) * rtot[m];
        o_bf[((size_t)(i0 + m) * B + bb) * (H * DH) + h * DH + dslice * 16 + lm]
            = f2bs(val);
    }
}

// ---------------------------------------------------------------------------
extern "C" void kernel_launch(void* const* d_in, const int* in_sizes, int n_in,
                              void* d_out, int out_size, void* d_ws, size_t ws_size,
                              hipStream_t stream)
{
    const float* x    = (const float*)d_in[0];   // [S, B, D]
    const float* pemb = (const float*)d_in[1];   // [S+M, D]
    const float* mem  = (const float*)d_in[2];   // [M, B, D]
    const float* u    = (const float*)d_in[3];   // [H, DH]
    const float* v    = (const float*)d_in[4];   // [H, DH]
    const float* Wkv  = (const float*)d_in[5];   // [D, 2*H*DH]
    const float* Wq   = (const float*)d_in[6];   // [D, H*DH]
    const float* Wpos = (const float*)d_in[7];   // [D, H*DH]
    const float* Wout = (const float*)d_in[8];   // [H*DH, D]
    float* out = (float*)d_out;                  // [S, B, D]

    char* p = (char*)d_ws;
    short* a_bf  = (short*)p; p += (size_t)4096 * 1024 * 2;    // mem||x  [0,8M)
    short* p_bf  = (short*)p; p += (size_t)2048 * 1024 * 2;    // [8M,12M)
    short* wkvt  = (short*)p; p += (size_t)2048 * 1024 * 2;    // [12M,16M)
    short* wqt   = (short*)p; p += (size_t)1024 * 1024 * 2;    // [16M,18M)
    short* wpt   = (short*)p; p += (size_t)1024 * 1024 * 2;    // [18M,20M)
    short* wot   = (short*)p; p += (size_t)1024 * 1024 * 2;    // [20M,22M)
    short* k_bf  = (short*)p; p += (size_t)B * H * J * DH * 2;
    short* vt_bf = (short*)p; p += (size_t)B * H * J * DH * 2;
    short* qu_bf = (short*)p; p += (size_t)B * H * S * DH * 2;
    short* qv_bf = (short*)p; p += (size_t)B * H * S * DH * 2;
    short* r_bf  = (short*)p; p += (size_t)H * J * DH * 2;
    short* o_bf  = (short*)p;

    prep<<<7424, 256, 0, stream>>>(mem, x, pemb, Wkv, Wq, Wpos, Wout,
                                   a_bf, p_bf, wkvt, wqt, wpt, wot);
    proj_fused<<<768, 256, 0, stream>>>(a_bf, p_bf, wkvt, wqt, wpt,
                                        k_bf, vt_bf, qu_bf, qv_bf, r_bf, u, v);
    attn_mfma<<<1024, 512, 0, stream>>>(
        qu_bf, qv_bf, k_bf, vt_bf, r_bf, o_bf);
    gemm_out<<<256, 256, 0, stream>>>(o_bf, wot, out);
}

// Round 14
// 304.013 us; speedup vs baseline: 1.0643x; 1.0643x over previous
//
#include <hip/hip_runtime.h>
#include <hip/hip_bf16.h>
#include <hip/hip_fp16.h>
#include <math.h>

#define D    1024
#define H    16
#define DH   64
#define S    1024
#define M    1024
#define B    2
#define J    2048          // M + S
#define SCALE 0.125f       // 1/sqrt(64)
#define SCALE_L2E 0.18033688f   // SCALE * log2(e): softmax uses bare exp2

typedef __attribute__((ext_vector_type(8))) short        bf16x8;
typedef __attribute__((ext_vector_type(4))) short        s16x4;
typedef __attribute__((ext_vector_type(8))) _Float16     h16x8;
typedef __attribute__((ext_vector_type(4))) _Float16     h16x4;
typedef __attribute__((ext_vector_type(8))) unsigned short us8;
typedef __attribute__((ext_vector_type(4))) unsigned short us4;
typedef __attribute__((ext_vector_type(4))) float        f32x4;

__device__ __forceinline__ short f2bs(float f) {
    __hip_bfloat16 t = __float2bfloat16(f);
    short r; __builtin_memcpy(&r, &t, 2); return r;
}
// fast bf16 pack (round-half-up); inputs finite non-negative (probs)
__device__ __forceinline__ unsigned short f2bf_fast(float f) {
    unsigned int u; __builtin_memcpy(&u, &f, 4);
    return (unsigned short)((u + 0x8000u) >> 16);
}

// async global->LDS, 16 bytes per lane
__device__ __forceinline__ void g2l16(const short* g, short* l) {
    __builtin_amdgcn_global_load_lds(
        (const __attribute__((address_space(1))) unsigned int*)g,
        (__attribute__((address_space(3))) unsigned int*)l, 16, 0, 0);
}

// ---------------------------------------------------------------------------
// prep: blocks [0,6144)  fp32->bf16 flat convert (mem||x -> a_bf, pemb -> p_bf)
//       blocks [6144,7424) 64x64 weight transpose+convert W[k][n] -> Wt[n][k]
// ---------------------------------------------------------------------------
__global__ __launch_bounds__(256)
void prep(const float* __restrict__ mem, const float* __restrict__ x,
          const float* __restrict__ pemb,
          const float* __restrict__ Wkv, const float* __restrict__ Wq,
          const float* __restrict__ Wpos, const float* __restrict__ Wout,
          short* __restrict__ a_bf, short* __restrict__ p_bf,
          short* __restrict__ wkvt, short* __restrict__ wqt,
          short* __restrict__ wpt,  short* __restrict__ wot)
{
    __shared__ float t[64][65];
    int blk = blockIdx.x;
    const int tid = threadIdx.x;
    if (blk < 6144) {
        const int idx = (blk * 256 + tid) * 4;
        const int TWO_M = 2 * 1024 * 1024;
        float4 v; short* dst;
        if (idx < TWO_M)          { v = *(const float4*)(mem  + idx);           dst = a_bf + idx; }
        else if (idx < 2 * TWO_M) { v = *(const float4*)(x    + idx - TWO_M);   dst = a_bf + idx; }
        else                      { v = *(const float4*)(pemb + idx - 2*TWO_M); dst = p_bf + idx - 2*TWO_M; }
        s16x4 o = { f2bs(v.x), f2bs(v.y), f2bs(v.z), f2bs(v.w) };
        *(s16x4*)dst = o;
        return;
    }
    blk -= 6144;
    const float* src; short* dst; int N, t0;
    if (blk < 512)       { src = Wkv;  dst = wkvt; N = 2048; t0 = blk; }
    else if (blk < 768)  { src = Wq;   dst = wqt;  N = 1024; t0 = blk - 512; }
    else if (blk < 1024) { src = Wpos; dst = wpt;  N = 1024; t0 = blk - 768; }
    else                 { src = Wout; dst = wot;  N = 1024; t0 = blk - 1024; }
    const int ntn = N >> 6;
    const int k0 = (t0 / ntn) * 64, n0 = (t0 % ntn) * 64;
    #pragma unroll
    for (int e = tid; e < 4096; e += 256) {
        int r = e >> 6, c = e & 63;
        t[r][c] = src[(size_t)(k0 + r) * N + n0 + c];
    }
    __syncthreads();
    #pragma unroll
    for (int e = tid; e < 4096; e += 256) {
        int nr = e >> 6, kc = e & 63;
        dst[(size_t)(n0 + nr) * 1024 + k0 + kc] = f2bs(t[kc][nr]);
    }
}

// ---------------------------------------------------------------------------
// Shared MFMA GEMM core: BM=BN=128, BK=64, 256 thr, K=1024.
// ---------------------------------------------------------------------------
__device__ __forceinline__ void gemm_core(const short* __restrict__ A,
                                          const short* __restrict__ Bt,
                                          short* As, short* Bs,
                                          int bm0, int bn0, int tid,
                                          f32x4 acc[4][4])
{
    const int w    = tid >> 6;
    const int wy   = w >> 1, wx = w & 1;
    const int lane = tid & 63;
    const int lm   = lane & 15;
    const int lq   = lane >> 4;

    for (int k0 = 0; k0 < 1024; k0 += 64) {
        const short* Ab = A  + (size_t)bm0 * 1024 + k0;
        const short* Bb = Bt + (size_t)bn0 * 1024 + k0;
        #pragma unroll
        for (int t = 0; t < 4; ++t) {
            int s = t * 256 + tid;
            int r = s >> 3, c = s & 7;
            int cg = c ^ (r & 7);
            g2l16(Ab + r * 1024 + cg * 8, As + s * 8);
            g2l16(Bb + r * 1024 + cg * 8, Bs + s * 8);
        }
        __syncthreads();
        #pragma unroll
        for (int kk = 0; kk < 2; ++kk) {
            bf16x8 af[4], bg[4];
            #pragma unroll
            for (int r4 = 0; r4 < 4; ++r4) {
                int ar = wy * 64 + r4 * 16 + lm;
                int kc = kk * 4 + lq;
                af[r4] = *(const bf16x8*)(As + ((ar << 3) + (kc ^ (ar & 7))) * 8);
            }
            #pragma unroll
            for (int c4 = 0; c4 < 4; ++c4) {
                int br = wx * 64 + c4 * 16 + lm;
                int kc = kk * 4 + lq;
                bg[c4] = *(const bf16x8*)(Bs + ((br << 3) + (kc ^ (br & 7))) * 8);
            }
            #pragma unroll
            for (int r4 = 0; r4 < 4; ++r4)
                #pragma unroll
                for (int c4 = 0; c4 < 4; ++c4)
                    acc[r4][c4] = __builtin_amdgcn_mfma_f32_16x16x32_bf16(
                        af[r4], bg[c4], acc[r4][c4], 0, 0, 0);
        }
        __syncthreads();
    }
}

// ---------------------------------------------------------------------------
// Fused kv/q/r projections. qu/qv scaled by SCALE*log2(e) (bare exp2 attn).
// R18 XCD-aware block remap (bijective: 768 = 8 x 96).
// ---------------------------------------------------------------------------
__global__ __launch_bounds__(256)
void proj_fused(const short* __restrict__ a_bf, const short* __restrict__ p_bf,
                const short* __restrict__ wkvt, const short* __restrict__ wqt,
                const short* __restrict__ wpt,
                short* __restrict__ k_bf, short* __restrict__ vt_bf,
                short* __restrict__ qu_bf, short* __restrict__ qv_bf,
                short* __restrict__ r_bf,
                const float* __restrict__ uvec, const float* __restrict__ vvec)
{
    __shared__ __align__(16) short As[128 * 64];
    __shared__ __align__(16) short Bs[128 * 64];

    // XCD remap: HW sends original id L to XCD L&7; logical id below makes
    // XCD x execute the contiguous logical range [x*96, (x+1)*96).
    int blk = (blockIdx.x & 7) * 96 + (blockIdx.x >> 3);

    int mode, bx, by;
    const short *A, *Bt;
    if (blk < 512)      { bx = blk & 15; by = blk >> 4;
                          if (bx >= 8) { mode = 4; A = wkvt; Bt = a_bf; }   // swapped V
                          else         { mode = 0; A = a_bf; Bt = wkvt; } }
    else if (blk < 640) { int b2 = blk - 512; mode = 1; bx = b2 & 7; by = b2 >> 3;
                          A = a_bf + (size_t)2048 * 1024; Bt = wqt; }
    else                { int b3 = blk - 640; mode = 2; bx = b3 & 7; by = b3 >> 3;
                          A = p_bf; Bt = wpt; }
    const int bn0 = (mode == 4) ? by * 128 : bx * 128;
    const int bm0 = (mode == 4) ? bx * 128 : by * 128;
    const int tid = threadIdx.x;
    const int w = tid >> 6, wy = w >> 1, wx = w & 1;
    const int lane = tid & 63, lm = lane & 15, lq = lane >> 4;

    f32x4 acc[4][4];
    #pragma unroll
    for (int r = 0; r < 4; ++r)
        #pragma unroll
        for (int c = 0; c < 4; ++c) acc[r][c] = (f32x4){0.f, 0.f, 0.f, 0.f};

    gemm_core(A, Bt, As, Bs, bm0, bn0, tid, acc);

    #pragma unroll
    for (int r4 = 0; r4 < 4; ++r4) {
        #pragma unroll
        for (int c4 = 0; c4 < 4; ++c4) {
            const int n = bn0 + wx * 64 + c4 * 16 + lm;
            float ubias = 0.f, vbias = 0.f;
            if (mode == 1) { ubias = uvec[n]; vbias = vvec[n]; }
            #pragma unroll
            for (int reg = 0; reg < 4; ++reg) {
                const int m = bm0 + wy * 64 + r4 * 16 + lq * 4 + reg;
                const float val = acc[r4][c4][reg];
                if (mode == 0) {
                    int j = m >> 1, b = m & 1;
                    int h = n >> 6, d = n & 63;
                    k_bf[(((size_t)b * H + h) * J + j) * DH + d] = f2bs(val);
                } else if (mode == 4) {
                    int n2 = m - 1024, h = n2 >> 6, d = n2 & 63;
                    int j = n >> 1, b = n & 1;
                    vt_bf[(((size_t)b * H + h) * DH + d) * J + j] = f2bs(val);
                } else if (mode == 1) {
                    int i = m >> 1, b = m & 1;
                    int h = n >> 6, d = n & 63;
                    size_t o = (((size_t)b * H + h) * S + i) * DH + d;
                    qu_bf[o] = f2bs((val + ubias) * SCALE_L2E);
                    qv_bf[o] = f2bs((val + vbias) * SCALE_L2E);
                } else {
                    int h = n >> 6, d = n & 63;
                    r_bf[((size_t)h * J + m) * DH + d] = f2bs(val);
                }
            }
        }
    }
}

// ---------------------------------------------------------------------------
// Output projection: M=2048, N=1024, fp32 out. BM=64, BN=128, 256 blocks,
// XCD-contiguous logical order.
// ---------------------------------------------------------------------------
__global__ __launch_bounds__(256)
void gemm_out(const short* __restrict__ A, const short* __restrict__ Bt,
              float* __restrict__ out)
{
    __shared__ __align__(16) short As[64 * 64];    // 8 KB
    __shared__ __align__(16) short Bs[128 * 64];   // 16 KB
    const int lb = (blockIdx.x & 7) * 32 + (blockIdx.x >> 3);  // XCD-contig
    const int bn0 = (lb & 7) * 128, bm0 = (lb >> 3) * 64;
    const int tid = threadIdx.x;
    const int w = tid >> 6;                 // 0..3 = column-split wave index
    const int lane = tid & 63, lm = lane & 15, lq = lane >> 4;

    f32x4 acc[4][2];
    #pragma unroll
    for (int r = 0; r < 4; ++r)
        #pragma unroll
        for (int c = 0; c < 2; ++c) acc[r][c] = (f32x4){0.f, 0.f, 0.f, 0.f};

    for (int k0 = 0; k0 < 1024; k0 += 64) {
        const short* Ab = A  + (size_t)bm0 * 1024 + k0;
        const short* Bb = Bt + (size_t)bn0 * 1024 + k0;
        #pragma unroll
        for (int t = 0; t < 2; ++t) {       // A: 64 rows
            int s = t * 256 + tid;
            int r = s >> 3, c = s & 7;
            int cg = c ^ (r & 7);
            g2l16(Ab + r * 1024 + cg * 8, As + s * 8);
        }
        #pragma unroll
        for (int t = 0; t < 4; ++t) {       // B: 128 rows
            int s = t * 256 + tid;
            int r = s >> 3, c = s & 7;
            int cg = c ^ (r & 7);
            g2l16(Bb + r * 1024 + cg * 8, Bs + s * 8);
        }
        __syncthreads();
        #pragma unroll
        for (int kk = 0; kk < 2; ++kk) {
            bf16x8 af[4], bg[2];
            #pragma unroll
            for (int r4 = 0; r4 < 4; ++r4) {
                int ar = r4 * 16 + lm;
                int kc = kk * 4 + lq;
                af[r4] = *(const bf16x8*)(As + ((ar << 3) + (kc ^ (ar & 7))) * 8);
            }
            #pragma unroll
            for (int c4 = 0; c4 < 2; ++c4) {
                int br = w * 32 + c4 * 16 + lm;
                int kc = kk * 4 + lq;
                bg[c4] = *(const bf16x8*)(Bs + ((br << 3) + (kc ^ (br & 7))) * 8);
            }
            #pragma unroll
            for (int r4 = 0; r4 < 4; ++r4)
                #pragma unroll
                for (int c4 = 0; c4 < 2; ++c4)
                    acc[r4][c4] = __builtin_amdgcn_mfma_f32_16x16x32_bf16(
                        af[r4], bg[c4], acc[r4][c4], 0, 0, 0);
        }
        __syncthreads();
    }

    #pragma unroll
    for (int r4 = 0; r4 < 4; ++r4)
        #pragma unroll
        for (int c4 = 0; c4 < 2; ++c4) {
            const int n = bn0 + w * 32 + c4 * 16 + lm;
            #pragma unroll
            for (int reg = 0; reg < 4; ++reg) {
                const int m = bm0 + r4 * 16 + lq * 4 + reg;
                out[(size_t)m * 1024 + n] = acc[r4][c4][reg];
            }
        }
}

// ---------------------------------------------------------------------------
// MFMA attention. R23 = R22 structure (fused jh loop, PV row-half split with
// 16 acc regs, direct epilogue) with NATURAL register allocation — R22's
// __launch_bounds__(512,4) forced a 128-unified cap and spilled (WRITE
// 4->94 MB, FETCH 16->64 MB, dur 168 us): third confirmation that forcing
// the allocator spills. Natural demand est: R21's 104 arch + 16 acc (pb
// deleted) + smaller epilogue ~ 104-120 unified. If <=128 the scheduler
// gives 4 waves/SIMD -> 2 blocks/CU (43%) WITHOUT spill; worst case stays
// at 22% but keeps the deleted epilogue LDS round-trip. Either way >= R21.
// ---------------------------------------------------------------------------
__device__ __forceinline__ int sidx(int m, int c) {   // m in [0,32), c in [0,1024)
    return (m << 10) + (c ^ (m << 3));
}

__global__ __launch_bounds__(512)
void attn_mfma(const short* __restrict__ qu_bf, const short* __restrict__ qv_bf,
               const short* __restrict__ k_bf,  const short* __restrict__ vt_bf,
               const short* __restrict__ r_bf,
               short* __restrict__ o_bf)
{
    __shared__ unsigned short sc[32 * 1024];   // 64 KB
    __shared__ float wsum[16][2][8];           // per-wave row partials
    __shared__ float rtot[32];                 // final inverse row sums
    __half* sch = (__half*)sc;

    // XCD-aware decode: L&7 = XCD; each XCD owns bh in [4*xcd, 4*xcd+4).
    const int L   = blockIdx.x;
    const int xcd = L & 7;
    const int pp  = L >> 3;                    // 0..127
    const int bh  = (xcd << 2) + (pp >> 5);    // 4 streams per XCD
    const int it  = pp & 31;

    const int i0  = it * 32;
    const int h   = bh & (H - 1);
    const int tid = threadIdx.x;
    const int w    = tid >> 6;       // 0..7
    const int lane = tid & 63;
    const int lm   = lane & 15;
    const int lq   = lane >> 4;
    const int dslice = w & 3, rh = w >> 2, mrp = rh * 16;

    const short* rbase = r_bf + (size_t)h * J * DH;
    const short* kbase = k_bf + (size_t)bh * J * DH;

    float sum0 = 0.f, sum1 = 0.f;
    f32x4 pa0 = {0.f,0.f,0.f,0.f}, pa1 = {0.f,0.f,0.f,0.f};
    f32x4 pa2 = {0.f,0.f,0.f,0.f}, pa3 = {0.f,0.f,0.f,0.f};

    #pragma unroll 1
    for (int jh = 0; jh < 2; ++jh) {
        const int cbeg = jh << 10, cend = cbeg + 1024;
        if (jh) __syncthreads();   // prev PV score reads done before overwrite

        // ---- Qv / Qw fragments (per iteration; short live ranges) ----
        const short* qvp0 = qv_bf + ((size_t)(bh * S + i0 + lm)) * DH + lq * 8;
        const short* qvp1 = qvp0 + 16 * DH;
        bf16x8 av00 = *(const bf16x8*)qvp0, av01 = *(const bf16x8*)(qvp0 + 32);
        bf16x8 av10 = *(const bf16x8*)qvp1, av11 = *(const bf16x8*)(qvp1 + 32);
        int r1a = i0 + 1 + lm;  if (r1a > S - 1) r1a = S - 1;   // clamped rows masked
        int r1b = i0 + 17 + lm; if (r1b > S - 1) r1b = S - 1;
        const short* qwp0 = qv_bf + ((size_t)(bh * S + r1a)) * DH + lq * 8;
        const short* qwp1 = qv_bf + ((size_t)(bh * S + r1b)) * DH + lq * 8;
        bf16x8 aw00 = *(const bf16x8*)qwp0, aw01 = *(const bf16x8*)(qwp0 + 32);
        bf16x8 aw10 = *(const bf16x8*)qwp1, aw11 = *(const bf16x8*)(qwp1 + 32);

        // ---- zero the pos hole column: row m, col i0+m+1025 (if in window) ----
        if (tid < 32) {
            int hole = i0 + tid + 1025;
            if (hole >= cbeg && hole < cend) sc[sidx(tid, hole - cbeg)] = 0;
        }

        // ---- pos main: col = i0 + 16t + lm + m - 1023; direct loads ----
        {
            int tmp = cbeg + 977 - i0;
            int tlo = tmp > 0 ? ((tmp + 15) >> 4) : 0;
            int thi = (cend + 1022 - i0) >> 4; if (thi > 127) thi = 127;
            for (int t = tlo + w; t <= thi; t += 8) {
                const short* rp = rbase + (size_t)(t * 16 + lm) * DH + lq * 8;
                bf16x8 b0 = *(const bf16x8*)rp, b1 = *(const bf16x8*)(rp + 32);
                f32x4 c0 = {0.f,0.f,0.f,0.f}, c1 = {0.f,0.f,0.f,0.f};
                __builtin_amdgcn_s_setprio(1);
                c0 = __builtin_amdgcn_mfma_f32_16x16x32_bf16(av00, b0, c0, 0, 0, 0);
                c1 = __builtin_amdgcn_mfma_f32_16x16x32_bf16(av10, b0, c1, 0, 0, 0);
                c0 = __builtin_amdgcn_mfma_f32_16x16x32_bf16(av01, b1, c0, 0, 0, 0);
                c1 = __builtin_amdgcn_mfma_f32_16x16x32_bf16(av11, b1, c1, 0, 0, 0);
                __builtin_amdgcn_s_setprio(0);
                int cb = i0 + t * 16 + lm - 1023 - cbeg;     // local col for m=0
                int base = i0 + 16 * t - 1023;               // scalar col_min
                if (base >= cbeg && base + 46 < cend) {
                    #pragma unroll
                    for (int r = 0; r < 4; ++r) {
                        int m0 = lq * 4 + r, m1 = m0 + 16;
                        sch[sidx(m0, cb + m0)] = __float2half(c0[r]);
                        sch[sidx(m1, cb + m1)] = __float2half(c1[r]);
                    }
                } else {
                    #pragma unroll
                    for (int r = 0; r < 4; ++r) {
                        int m0 = lq * 4 + r, m1 = m0 + 16;
                        int cA = cb + m0, cB = cb + m1;
                        if (cA >= 0 && cA < 1024) sch[sidx(m0, cA)] = __float2half(c0[r]);
                        if (cB >= 0 && cB < 1024) sch[sidx(m1, cB)] = __float2half(c1[r]);
                    }
                }
            }
        }

        // ---- pos wrap: col = i0 + 16t + lm + m + 1026, rows Qv[i+1] ----
        {
            int tmpw = cbeg - 1072 - i0;
            int tlw = tmpw > 0 ? ((tmpw + 15) >> 4) : 0;
            int thw = (cend - 1027 - i0) >> 4; if (thw > 127) thw = 127;
            for (int t = tlw + w; t <= thw; t += 8) {
                const short* rp = rbase + (size_t)(t * 16 + lm) * DH + lq * 8;
                bf16x8 b0 = *(const bf16x8*)rp, b1 = *(const bf16x8*)(rp + 32);
                f32x4 c0 = {0.f,0.f,0.f,0.f}, c1 = {0.f,0.f,0.f,0.f};
                __builtin_amdgcn_s_setprio(1);
                c0 = __builtin_amdgcn_mfma_f32_16x16x32_bf16(aw00, b0, c0, 0, 0, 0);
                c1 = __builtin_amdgcn_mfma_f32_16x16x32_bf16(aw10, b0, c1, 0, 0, 0);
                c0 = __builtin_amdgcn_mfma_f32_16x16x32_bf16(aw01, b1, c0, 0, 0, 0);
                c1 = __builtin_amdgcn_mfma_f32_16x16x32_bf16(aw11, b1, c1, 0, 0, 0);
                __builtin_amdgcn_s_setprio(0);
                int cb = i0 + t * 16 + lm + 1026 - cbeg;
                int base = i0 + 16 * t + 1026;
                if (base >= cbeg && base + 46 < cend) {
                    #pragma unroll
                    for (int r = 0; r < 4; ++r) {
                        int m0 = lq * 4 + r, m1 = m0 + 16;
                        sch[sidx(m0, cb + m0)] = __float2half(c0[r]);
                        sch[sidx(m1, cb + m1)] = __float2half(c1[r]);
                    }
                } else {
                    #pragma unroll
                    for (int r = 0; r < 4; ++r) {
                        int m0 = lq * 4 + r, m1 = m0 + 16;
                        int cA = cb + m0, cB = cb + m1;
                        if (cA >= 0 && cA < 1024) sch[sidx(m0, cA)] = __float2half(c0[r]);
                        if (cB >= 0 && cB < 1024) sch[sidx(m1, cB)] = __float2half(c1[r]);
                    }
                }
            }
        }

        // ---- prefetch first content K-tile before the barrier ----
        bf16x8 kb0, kb1;
        {
            int t0 = jh * 64 + w + 8 * (it & 7);
            const short* kp0 = kbase + (size_t)(t0 * 16 + lm) * DH + lq * 8;
            kb0 = *(const bf16x8*)kp0; kb1 = *(const bf16x8*)(kp0 + 32);
        }
        __syncthreads();

        // ---- Qu fragments ----
        const short* qup0 = qu_bf + ((size_t)(bh * S + i0 + lm)) * DH + lq * 8;
        const short* qup1 = qup0 + 16 * DH;
        bf16x8 au00 = *(const bf16x8*)qup0, au01 = *(const bf16x8*)(qup0 + 32);
        bf16x8 au10 = *(const bf16x8*)qup1, au11 = *(const bf16x8*)(qup1 + 32);

        // ---- content + softmax FUSED; depth-1 rolling K prefetch ----
        #pragma unroll 1
        for (int g = 0; g < 8; ++g) {
            bf16x8 nb0, nb1;
            if (g + 1 < 8) {
                int u = jh * 64 + w + 8 * ((g + 1 + it) & 7);
                const short* np = kbase + (size_t)(u * 16 + lm) * DH + lq * 8;
                nb0 = *(const bf16x8*)np; nb1 = *(const bf16x8*)(np + 32);
            }
            int t = jh * 64 + w + 8 * ((g + it) & 7);
            int lc = t * 16 - cbeg;                  // 16-aligned local col base
            int aA = sidx(lm,      lc + lq * 4);     // 4 consecutive u16, 8B-aligned
            int aB = sidx(lm + 16, lc + lq * 4);
            h16x4 hA = *(const h16x4*)(sc + aA);
            h16x4 hB = *(const h16x4*)(sc + aB);
            f32x4 c0, c1;
            #pragma unroll
            for (int r = 0; r < 4; ++r) { c0[r] = (float)hA[r]; c1[r] = (float)hB[r]; }
            __builtin_amdgcn_s_setprio(1);
            c0 = __builtin_amdgcn_mfma_f32_16x16x32_bf16(kb0, au00, c0, 0, 0, 0);
            c1 = __builtin_amdgcn_mfma_f32_16x16x32_bf16(kb0, au10, c1, 0, 0, 0);
            c0 = __builtin_amdgcn_mfma_f32_16x16x32_bf16(kb1, au01, c0, 0, 0, 0);
            c1 = __builtin_amdgcn_mfma_f32_16x16x32_bf16(kb1, au11, c1, 0, 0, 0);
            __builtin_amdgcn_s_setprio(0);
            us4 oA, oB;
            #pragma unroll
            for (int r = 0; r < 4; ++r) {
                float e0 = __builtin_amdgcn_exp2f(c0[r]);
                float e1 = __builtin_amdgcn_exp2f(c1[r]);
                sum0 += e0; sum1 += e1;
                oA[r] = f2bf_fast(e0);
                oB[r] = f2bf_fast(e1);
            }
            *(us4*)(sc + aA) = oA;
            *(us4*)(sc + aB) = oB;
            kb0 = nb0; kb1 = nb1;
        }

        // ---- prefetch first PV V-chunk before the barrier ----
        const short* vtb = vt_bf + ((size_t)bh * DH + dslice * 16 + lm) * J + cbeg;
        bf16x8 cv0, cv1, cv2, cv3;
        {
            int j0 = (it & 7) * 128;
            cv0 = *(const bf16x8*)(vtb + j0 +  0 + lq * 8);
            cv1 = *(const bf16x8*)(vtb + j0 + 32 + lq * 8);
            cv2 = *(const bf16x8*)(vtb + j0 + 64 + lq * 8);
            cv3 = *(const bf16x8*)(vtb + j0 + 96 + lq * 8);
        }
        __syncthreads();

        // ---- PV: wave -> (d-slice, row-half); 8 x 128 j per jh ----
        #pragma unroll 1
        for (int jo = 0; jo < 8; ++jo) {
            bf16x8 nv0, nv1, nv2, nv3;
            if (jo < 7) {
                int jn = ((jo + 1 + it) & 7) * 128;
                nv0 = *(const bf16x8*)(vtb + jn +  0 + lq * 8);
                nv1 = *(const bf16x8*)(vtb + jn + 32 + lq * 8);
                nv2 = *(const bf16x8*)(vtb + jn + 64 + lq * 8);
                nv3 = *(const bf16x8*)(vtb + jn + 96 + lq * 8);
            }
            int jc = ((jo + it) & 7) * 128;
            bf16x8 a0 = *(const bf16x8*)(sc + sidx(mrp + lm, jc +  0 + lq * 8));
            bf16x8 a1 = *(const bf16x8*)(sc + sidx(mrp + lm, jc + 32 + lq * 8));
            bf16x8 a2 = *(const bf16x8*)(sc + sidx(mrp + lm, jc + 64 + lq * 8));
            bf16x8 a3 = *(const bf16x8*)(sc + sidx(mrp + lm, jc + 96 + lq * 8));
            __builtin_amdgcn_s_setprio(1);
            pa0 = __builtin_amdgcn_mfma_f32_16x16x32_bf16(a0, cv0, pa0, 0, 0, 0);
            pa1 = __builtin_amdgcn_mfma_f32_16x16x32_bf16(a1, cv1, pa1, 0, 0, 0);
            pa2 = __builtin_amdgcn_mfma_f32_16x16x32_bf16(a2, cv2, pa2, 0, 0, 0);
            pa3 = __builtin_amdgcn_mfma_f32_16x16x32_bf16(a3, cv3, pa3, 0, 0, 0);
            __builtin_amdgcn_s_setprio(0);
            if (jo < 7) { cv0 = nv0; cv1 = nv1; cv2 = nv2; cv3 = nv3; }
        }
    }

    // ---- epilogue: row sums -> rtot; direct normalized o_bf write ----
    sum0 += __shfl_xor(sum0, 16); sum0 += __shfl_xor(sum0, 32);
    sum1 += __shfl_xor(sum1, 16); sum1 += __shfl_xor(sum1, 32);
    if (lane < 16) { wsum[lane][0][w] = sum0; wsum[lane][1][w] = sum1; }
    __syncthreads();
    if (tid < 32) {
        float s = 0.f;
        #pragma unroll
        for (int ww = 0; ww < 8; ++ww) s += wsum[tid & 15][tid >> 4][ww];
        rtot[tid] = 1.0f / s;
    }
    __syncthreads();

    const int bb = bh >> 4;
    #pragma unroll
    for (int r = 0; r < 4; ++r) {
        int m = mrp + lq * 4 + r;            // this wave's rows
        float val = (pa0[r] + pa1[r] + pa2[r] + pa3[r]) * rtot[m];
        o_bf[((size_t)(i0 + m) * B + bb) * (H * DH) + h * DH + dslice * 16 + lm]
            = f2bs(val);
    }
}

// ---------------------------------------------------------------------------
extern "C" void kernel_launch(void* const* d_in, const int* in_sizes, int n_in,
                              void* d_out, int out_size, void* d_ws, size_t ws_size,
                              hipStream_t stream)
{
    const float* x    = (const float*)d_in[0];   // [S, B, D]
    const float* pemb = (const float*)d_in[1];   // [S+M, D]
    const float* mem  = (const float*)d_in[2];   // [M, B, D]
    const float* u    = (const float*)d_in[3];   // [H, DH]
    const float* v    = (const float*)d_in[4];   // [H, DH]
    const float* Wkv  = (const float*)d_in[5];   // [D, 2*H*DH]
    const float* Wq   = (const float*)d_in[6];   // [D, H*DH]
    const float* Wpos = (const float*)d_in[7];   // [D, H*DH]
    const float* Wout = (const float*)d_in[8];   // [H*DH, D]
    float* out = (float*)d_out;                  // [S, B, D]

    char* p = (char*)d_ws;
    short* a_bf  = (short*)p; p += (size_t)4096 * 1024 * 2;    // mem||x  [0,8M)
    short* p_bf  = (short*)p; p += (size_t)2048 * 1024 * 2;    // [8M,12M)
    short* wkvt  = (short*)p; p += (size_t)2048 * 1024 * 2;    // [12M,16M)
    short* wqt   = (short*)p; p += (size_t)1024 * 1024 * 2;    // [16M,18M)
    short* wpt   = (short*)p; p += (size_t)1024 * 1024 * 2;    // [18M,20M)
    short* wot   = (short*)p; p += (size_t)1024 * 1024 * 2;    // [20M,22M)
    short* k_bf  = (short*)p; p += (size_t)B * H * J * DH * 2;
    short* vt_bf = (short*)p; p += (size_t)B * H * J * DH * 2;
    short* qu_bf = (short*)p; p += (size_t)B * H * S * DH * 2;
    short* qv_bf = (short*)p; p += (size_t)B * H * S * DH * 2;
    short* r_bf  = (short*)p; p += (size_t)H * J * DH * 2;
    short* o_bf  = (short*)p;

    prep<<<7424, 256, 0, stream>>>(mem, x, pemb, Wkv, Wq, Wpos, Wout,
                                   a_bf, p_bf, wkvt, wqt, wpt, wot);
    proj_fused<<<768, 256, 0, stream>>>(a_bf, p_bf, wkvt, wqt, wpt,
                                        k_bf, vt_bf, qu_bf, qv_bf, r_bf, u, v);
    attn_mfma<<<1024, 512, 0, stream>>>(
        qu_bf, qv_bf, k_bf, vt_bf, r_bf, o_bf);
    gemm_out<<<256, 256, 0, stream>>>(o_bf, wot, out);
}

// Round 15
// 277.926 us; speedup vs baseline: 1.1642x; 1.0939x over previous
//
#include <hip/hip_runtime.h>
#include <hip/hip_bf16.h>
#include <hip/hip_fp16.h>
#include <math.h>

#define D    1024
#define H    16
#define DH   64
#define S    1024
#define M    1024
#define B    2
#define J    2048          // M + S
#define SCALE 0.125f       // 1/sqrt(64)
#define SCALE_L2E 0.18033688f   // SCALE * log2(e): softmax uses bare exp2

typedef __attribute__((ext_vector_type(8))) short        bf16x8;
typedef __attribute__((ext_vector_type(4))) short        s16x4;
typedef __attribute__((ext_vector_type(8))) _Float16     h16x8;
typedef __attribute__((ext_vector_type(4))) _Float16     h16x4;
typedef __attribute__((ext_vector_type(8))) unsigned short us8;
typedef __attribute__((ext_vector_type(4))) unsigned short us4;
typedef __attribute__((ext_vector_type(4))) float        f32x4;

__device__ __forceinline__ short f2bs(float f) {
    __hip_bfloat16 t = __float2bfloat16(f);
    short r; __builtin_memcpy(&r, &t, 2); return r;
}
// fast bf16 pack (round-half-up); inputs finite non-negative (probs)
__device__ __forceinline__ unsigned short f2bf_fast(float f) {
    unsigned int u; __builtin_memcpy(&u, &f, 4);
    return (unsigned short)((u + 0x8000u) >> 16);
}

// async global->LDS, 16 bytes per lane
__device__ __forceinline__ void g2l16(const short* g, short* l) {
    __builtin_amdgcn_global_load_lds(
        (const __attribute__((address_space(1))) unsigned int*)g,
        (__attribute__((address_space(3))) unsigned int*)l, 16, 0, 0);
}

// ---------------------------------------------------------------------------
// prep: blocks [0,6144)  fp32->bf16 flat convert (mem||x -> a_bf, pemb -> p_bf)
//       blocks [6144,7424) 64x64 weight transpose+convert W[k][n] -> Wt[n][k]
// ---------------------------------------------------------------------------
__global__ __launch_bounds__(256)
void prep(const float* __restrict__ mem, const float* __restrict__ x,
          const float* __restrict__ pemb,
          const float* __restrict__ Wkv, const float* __restrict__ Wq,
          const float* __restrict__ Wpos, const float* __restrict__ Wout,
          short* __restrict__ a_bf, short* __restrict__ p_bf,
          short* __restrict__ wkvt, short* __restrict__ wqt,
          short* __restrict__ wpt,  short* __restrict__ wot)
{
    __shared__ float t[64][65];
    int blk = blockIdx.x;
    const int tid = threadIdx.x;
    if (blk < 6144) {
        const int idx = (blk * 256 + tid) * 4;
        const int TWO_M = 2 * 1024 * 1024;
        float4 v; short* dst;
        if (idx < TWO_M)          { v = *(const float4*)(mem  + idx);           dst = a_bf + idx; }
        else if (idx < 2 * TWO_M) { v = *(const float4*)(x    + idx - TWO_M);   dst = a_bf + idx; }
        else                      { v = *(const float4*)(pemb + idx - 2*TWO_M); dst = p_bf + idx - 2*TWO_M; }
        s16x4 o = { f2bs(v.x), f2bs(v.y), f2bs(v.z), f2bs(v.w) };
        *(s16x4*)dst = o;
        return;
    }
    blk -= 6144;
    const float* src; short* dst; int N, t0;
    if (blk < 512)       { src = Wkv;  dst = wkvt; N = 2048; t0 = blk; }
    else if (blk < 768)  { src = Wq;   dst = wqt;  N = 1024; t0 = blk - 512; }
    else if (blk < 1024) { src = Wpos; dst = wpt;  N = 1024; t0 = blk - 768; }
    else                 { src = Wout; dst = wot;  N = 1024; t0 = blk - 1024; }
    const int ntn = N >> 6;
    const int k0 = (t0 / ntn) * 64, n0 = (t0 % ntn) * 64;
    #pragma unroll
    for (int e = tid; e < 4096; e += 256) {
        int r = e >> 6, c = e & 63;
        t[r][c] = src[(size_t)(k0 + r) * N + n0 + c];
    }
    __syncthreads();
    #pragma unroll
    for (int e = tid; e < 4096; e += 256) {
        int nr = e >> 6, kc = e & 63;
        dst[(size_t)(n0 + nr) * 1024 + k0 + kc] = f2bs(t[kc][nr]);
    }
}

// ---------------------------------------------------------------------------
// Shared MFMA GEMM core: BM=BN=128, BK=64, 256 thr, K=1024.
// ---------------------------------------------------------------------------
__device__ __forceinline__ void gemm_core(const short* __restrict__ A,
                                          const short* __restrict__ Bt,
                                          short* As, short* Bs,
                                          int bm0, int bn0, int tid,
                                          f32x4 acc[4][4])
{
    const int w    = tid >> 6;
    const int wy   = w >> 1, wx = w & 1;
    const int lane = tid & 63;
    const int lm   = lane & 15;
    const int lq   = lane >> 4;

    for (int k0 = 0; k0 < 1024; k0 += 64) {
        const short* Ab = A  + (size_t)bm0 * 1024 + k0;
        const short* Bb = Bt + (size_t)bn0 * 1024 + k0;
        #pragma unroll
        for (int t = 0; t < 4; ++t) {
            int s = t * 256 + tid;
            int r = s >> 3, c = s & 7;
            int cg = c ^ (r & 7);
            g2l16(Ab + r * 1024 + cg * 8, As + s * 8);
            g2l16(Bb + r * 1024 + cg * 8, Bs + s * 8);
        }
        __syncthreads();
        #pragma unroll
        for (int kk = 0; kk < 2; ++kk) {
            bf16x8 af[4], bg[4];
            #pragma unroll
            for (int r4 = 0; r4 < 4; ++r4) {
                int ar = wy * 64 + r4 * 16 + lm;
                int kc = kk * 4 + lq;
                af[r4] = *(const bf16x8*)(As + ((ar << 3) + (kc ^ (ar & 7))) * 8);
            }
            #pragma unroll
            for (int c4 = 0; c4 < 4; ++c4) {
                int br = wx * 64 + c4 * 16 + lm;
                int kc = kk * 4 + lq;
                bg[c4] = *(const bf16x8*)(Bs + ((br << 3) + (kc ^ (br & 7))) * 8);
            }
            #pragma unroll
            for (int r4 = 0; r4 < 4; ++r4)
                #pragma unroll
                for (int c4 = 0; c4 < 4; ++c4)
                    acc[r4][c4] = __builtin_amdgcn_mfma_f32_16x16x32_bf16(
                        af[r4], bg[c4], acc[r4][c4], 0, 0, 0);
        }
        __syncthreads();
    }
}

// ---------------------------------------------------------------------------
// Fused kv/q/r projections. qu/qv scaled by SCALE*log2(e) (bare exp2 attn).
// XCD-aware block remap (bijective: 768 = 8 x 96).
// ---------------------------------------------------------------------------
__global__ __launch_bounds__(256)
void proj_fused(const short* __restrict__ a_bf, const short* __restrict__ p_bf,
                const short* __restrict__ wkvt, const short* __restrict__ wqt,
                const short* __restrict__ wpt,
                short* __restrict__ k_bf, short* __restrict__ vt_bf,
                short* __restrict__ qu_bf, short* __restrict__ qv_bf,
                short* __restrict__ r_bf,
                const float* __restrict__ uvec, const float* __restrict__ vvec)
{
    __shared__ __align__(16) short As[128 * 64];
    __shared__ __align__(16) short Bs[128 * 64];

    // XCD remap: HW sends original id L to XCD L&7; logical id below makes
    // XCD x execute the contiguous logical range [x*96, (x+1)*96).
    int blk = (blockIdx.x & 7) * 96 + (blockIdx.x >> 3);

    int mode, bx, by;
    const short *A, *Bt;
    if (blk < 512)      { bx = blk & 15; by = blk >> 4;
                          if (bx >= 8) { mode = 4; A = wkvt; Bt = a_bf; }   // swapped V
                          else         { mode = 0; A = a_bf; Bt = wkvt; } }
    else if (blk < 640) { int b2 = blk - 512; mode = 1; bx = b2 & 7; by = b2 >> 3;
                          A = a_bf + (size_t)2048 * 1024; Bt = wqt; }
    else                { int b3 = blk - 640; mode = 2; bx = b3 & 7; by = b3 >> 3;
                          A = p_bf; Bt = wpt; }
    const int bn0 = (mode == 4) ? by * 128 : bx * 128;
    const int bm0 = (mode == 4) ? bx * 128 : by * 128;
    const int tid = threadIdx.x;
    const int w = tid >> 6, wy = w >> 1, wx = w & 1;
    const int lane = tid & 63, lm = lane & 15, lq = lane >> 4;

    f32x4 acc[4][4];
    #pragma unroll
    for (int r = 0; r < 4; ++r)
        #pragma unroll
        for (int c = 0; c < 4; ++c) acc[r][c] = (f32x4){0.f, 0.f, 0.f, 0.f};

    gemm_core(A, Bt, As, Bs, bm0, bn0, tid, acc);

    #pragma unroll
    for (int r4 = 0; r4 < 4; ++r4) {
        #pragma unroll
        for (int c4 = 0; c4 < 4; ++c4) {
            const int n = bn0 + wx * 64 + c4 * 16 + lm;
            float ubias = 0.f, vbias = 0.f;
            if (mode == 1) { ubias = uvec[n]; vbias = vvec[n]; }
            #pragma unroll
            for (int reg = 0; reg < 4; ++reg) {
                const int m = bm0 + wy * 64 + r4 * 16 + lq * 4 + reg;
                const float val = acc[r4][c4][reg];
                if (mode == 0) {
                    int j = m >> 1, b = m & 1;
                    int h = n >> 6, d = n & 63;
                    k_bf[(((size_t)b * H + h) * J + j) * DH + d] = f2bs(val);
                } else if (mode == 4) {
                    int n2 = m - 1024, h = n2 >> 6, d = n2 & 63;
                    int j = n >> 1, b = n & 1;
                    vt_bf[(((size_t)b * H + h) * DH + d) * J + j] = f2bs(val);
                } else if (mode == 1) {
                    int i = m >> 1, b = m & 1;
                    int h = n >> 6, d = n & 63;
                    size_t o = (((size_t)b * H + h) * S + i) * DH + d;
                    qu_bf[o] = f2bs((val + ubias) * SCALE_L2E);
                    qv_bf[o] = f2bs((val + vbias) * SCALE_L2E);
                } else {
                    int h = n >> 6, d = n & 63;
                    r_bf[((size_t)h * J + m) * DH + d] = f2bs(val);
                }
            }
        }
    }
}

// ---------------------------------------------------------------------------
// Output projection: M=2048, N=1024, fp32 out. BM=64, BN=128, 256 blocks,
// XCD-contiguous logical order.
// ---------------------------------------------------------------------------
__global__ __launch_bounds__(256)
void gemm_out(const short* __restrict__ A, const short* __restrict__ Bt,
              float* __restrict__ out)
{
    __shared__ __align__(16) short As[64 * 64];    // 8 KB
    __shared__ __align__(16) short Bs[128 * 64];   // 16 KB
    const int lb = (blockIdx.x & 7) * 32 + (blockIdx.x >> 3);  // XCD-contig
    const int bn0 = (lb & 7) * 128, bm0 = (lb >> 3) * 64;
    const int tid = threadIdx.x;
    const int w = tid >> 6;                 // 0..3 = column-split wave index
    const int lane = tid & 63, lm = lane & 15, lq = lane >> 4;

    f32x4 acc[4][2];
    #pragma unroll
    for (int r = 0; r < 4; ++r)
        #pragma unroll
        for (int c = 0; c < 2; ++c) acc[r][c] = (f32x4){0.f, 0.f, 0.f, 0.f};

    for (int k0 = 0; k0 < 1024; k0 += 64) {
        const short* Ab = A  + (size_t)bm0 * 1024 + k0;
        const short* Bb = Bt + (size_t)bn0 * 1024 + k0;
        #pragma unroll
        for (int t = 0; t < 2; ++t) {       // A: 64 rows
            int s = t * 256 + tid;
            int r = s >> 3, c = s & 7;
            int cg = c ^ (r & 7);
            g2l16(Ab + r * 1024 + cg * 8, As + s * 8);
        }
        #pragma unroll
        for (int t = 0; t < 4; ++t) {       // B: 128 rows
            int s = t * 256 + tid;
            int r = s >> 3, c = s & 7;
            int cg = c ^ (r & 7);
            g2l16(Bb + r * 1024 + cg * 8, Bs + s * 8);
        }
        __syncthreads();
        #pragma unroll
        for (int kk = 0; kk < 2; ++kk) {
            bf16x8 af[4], bg[2];
            #pragma unroll
            for (int r4 = 0; r4 < 4; ++r4) {
                int ar = r4 * 16 + lm;
                int kc = kk * 4 + lq;
                af[r4] = *(const bf16x8*)(As + ((ar << 3) + (kc ^ (ar & 7))) * 8);
            }
            #pragma unroll
            for (int c4 = 0; c4 < 2; ++c4) {
                int br = w * 32 + c4 * 16 + lm;
                int kc = kk * 4 + lq;
                bg[c4] = *(const bf16x8*)(Bs + ((br << 3) + (kc ^ (br & 7))) * 8);
            }
            #pragma unroll
            for (int r4 = 0; r4 < 4; ++r4)
                #pragma unroll
                for (int c4 = 0; c4 < 2; ++c4)
                    acc[r4][c4] = __builtin_amdgcn_mfma_f32_16x16x32_bf16(
                        af[r4], bg[c4], acc[r4][c4], 0, 0, 0);
        }
        __syncthreads();
    }

    #pragma unroll
    for (int r4 = 0; r4 < 4; ++r4)
        #pragma unroll
        for (int c4 = 0; c4 < 2; ++c4) {
            const int n = bn0 + w * 32 + c4 * 16 + lm;
            #pragma unroll
            for (int reg = 0; reg < 4; ++reg) {
                const int m = bm0 + r4 * 16 + lq * 4 + reg;
                out[(size_t)m * 1024 + n] = acc[r4][c4][reg];
            }
        }
}

// ---------------------------------------------------------------------------
// MFMA attention — R25 = revert to R21, the measured session optimum
// (276.15 us total; attn 117.6 us). One block owns (bh, it) and loops both
// jh halves with PV accumulators (pa+pb, j-quarter split) and softmax row
// sums live in registers; attn_combine deleted. Direct pos loads, depth-1
// content K prefetch (prefetch fat was twice proven neutral and R23 showed
// longer PV serial chains HURT at 1-block residency). Mapped landscape:
//  - 2-blocks/CU needs <=64 reported VGPR (R0/R22 vs R21/R23) — unreachable
//    for the fused kernel; it runs at 1 block/CU and still beats the split
//    2-block variants (117.6 vs 121.6+combine).
//  - Forced launch_bounds min-waves ALWAYS spills (R10/R15/R22).
//  - Occupancy/LDS/latency/VALU levers all neutral (R11-R19): the kernel is
//    bound by its per-phase serial dependency structure.
// ---------------------------------------------------------------------------
__device__ __forceinline__ int sidx(int m, int c) {   // m in [0,32), c in [0,1024)
    return (m << 10) + (c ^ (m << 3));
}

__global__ __launch_bounds__(512)
void attn_mfma(const short* __restrict__ qu_bf, const short* __restrict__ qv_bf,
               const short* __restrict__ k_bf,  const short* __restrict__ vt_bf,
               const short* __restrict__ r_bf,
               short* __restrict__ o_bf)
{
    __shared__ unsigned short sc[32 * 1024];   // 64 KB
    __shared__ float wsum[16][2][8];           // per-wave row partials
    __shared__ float rtot[32];                 // final inverse row sums
    __half* sch = (__half*)sc;
    float*  scF = (float*)sc;                  // reused after PV reads

    // XCD-aware decode: L&7 = XCD; each XCD owns bh in [4*xcd, 4*xcd+4).
    const int L   = blockIdx.x;
    const int xcd = L & 7;
    const int pp  = L >> 3;                    // 0..127
    const int bh  = (xcd << 2) + (pp >> 5);    // 4 streams per XCD
    const int it  = pp & 31;

    const int i0  = it * 32;
    const int h   = bh & (H - 1);
    const int tid = threadIdx.x;
    const int w    = tid >> 6;       // 0..7
    const int lane = tid & 63;
    const int lm   = lane & 15;
    const int lq   = lane >> 4;
    const int dslice = w & 3, jq = w >> 2;

    const short* rbase = r_bf + (size_t)h * J * DH;
    const short* kbase = k_bf + (size_t)bh * J * DH;

    float sum0 = 0.f, sum1 = 0.f;
    f32x4 pa0 = {0.f,0.f,0.f,0.f}, pa1 = {0.f,0.f,0.f,0.f};
    f32x4 pa2 = {0.f,0.f,0.f,0.f}, pa3 = {0.f,0.f,0.f,0.f};
    f32x4 pb0 = {0.f,0.f,0.f,0.f}, pb1 = {0.f,0.f,0.f,0.f};
    f32x4 pb2 = {0.f,0.f,0.f,0.f}, pb3 = {0.f,0.f,0.f,0.f};

    #pragma unroll 1
    for (int jh = 0; jh < 2; ++jh) {
        const int cbeg = jh << 10, cend = cbeg + 1024;
        if (jh) __syncthreads();   // prev PV score reads done before overwrite

        // ---- Qv / Qw fragments (per iteration; short live ranges) ----
        const short* qvp0 = qv_bf + ((size_t)(bh * S + i0 + lm)) * DH + lq * 8;
        const short* qvp1 = qvp0 + 16 * DH;
        bf16x8 av00 = *(const bf16x8*)qvp0, av01 = *(const bf16x8*)(qvp0 + 32);
        bf16x8 av10 = *(const bf16x8*)qvp1, av11 = *(const bf16x8*)(qvp1 + 32);
        int r1a = i0 + 1 + lm;  if (r1a > S - 1) r1a = S - 1;   // clamped rows masked
        int r1b = i0 + 17 + lm; if (r1b > S - 1) r1b = S - 1;
        const short* qwp0 = qv_bf + ((size_t)(bh * S + r1a)) * DH + lq * 8;
        const short* qwp1 = qv_bf + ((size_t)(bh * S + r1b)) * DH + lq * 8;
        bf16x8 aw00 = *(const bf16x8*)qwp0, aw01 = *(const bf16x8*)(qwp0 + 32);
        bf16x8 aw10 = *(const bf16x8*)qwp1, aw11 = *(const bf16x8*)(qwp1 + 32);

        // ---- zero the pos hole column: row m, col i0+m+1025 (if in window) ----
        if (tid < 32) {
            int hole = i0 + tid + 1025;
            if (hole >= cbeg && hole < cend) sc[sidx(tid, hole - cbeg)] = 0;
        }

        // ---- pos main: col = i0 + 16t + lm + m - 1023; direct loads ----
        {
            int tmp = cbeg + 977 - i0;
            int tlo = tmp > 0 ? ((tmp + 15) >> 4) : 0;
            int thi = (cend + 1022 - i0) >> 4; if (thi > 127) thi = 127;
            for (int t = tlo + w; t <= thi; t += 8) {
                const short* rp = rbase + (size_t)(t * 16 + lm) * DH + lq * 8;
                bf16x8 b0 = *(const bf16x8*)rp, b1 = *(const bf16x8*)(rp + 32);
                f32x4 c0 = {0.f,0.f,0.f,0.f}, c1 = {0.f,0.f,0.f,0.f};
                __builtin_amdgcn_s_setprio(1);
                c0 = __builtin_amdgcn_mfma_f32_16x16x32_bf16(av00, b0, c0, 0, 0, 0);
                c1 = __builtin_amdgcn_mfma_f32_16x16x32_bf16(av10, b0, c1, 0, 0, 0);
                c0 = __builtin_amdgcn_mfma_f32_16x16x32_bf16(av01, b1, c0, 0, 0, 0);
                c1 = __builtin_amdgcn_mfma_f32_16x16x32_bf16(av11, b1, c1, 0, 0, 0);
                __builtin_amdgcn_s_setprio(0);
                int cb = i0 + t * 16 + lm - 1023 - cbeg;     // local col for m=0
                int base = i0 + 16 * t - 1023;               // scalar col_min
                if (base >= cbeg && base + 46 < cend) {
                    #pragma unroll
                    for (int r = 0; r < 4; ++r) {
                        int m0 = lq * 4 + r, m1 = m0 + 16;
                        sch[sidx(m0, cb + m0)] = __float2half(c0[r]);
                        sch[sidx(m1, cb + m1)] = __float2half(c1[r]);
                    }
                } else {
                    #pragma unroll
                    for (int r = 0; r < 4; ++r) {
                        int m0 = lq * 4 + r, m1 = m0 + 16;
                        int cA = cb + m0, cB = cb + m1;
                        if (cA >= 0 && cA < 1024) sch[sidx(m0, cA)] = __float2half(c0[r]);
                        if (cB >= 0 && cB < 1024) sch[sidx(m1, cB)] = __float2half(c1[r]);
                    }
                }
            }
        }

        // ---- pos wrap: col = i0 + 16t + lm + m + 1026, rows Qv[i+1] ----
        {
            int tmpw = cbeg - 1072 - i0;
            int tlw = tmpw > 0 ? ((tmpw + 15) >> 4) : 0;
            int thw = (cend - 1027 - i0) >> 4; if (thw > 127) thw = 127;
            for (int t = tlw + w; t <= thw; t += 8) {
                const short* rp = rbase + (size_t)(t * 16 + lm) * DH + lq * 8;
                bf16x8 b0 = *(const bf16x8*)rp, b1 = *(const bf16x8*)(rp + 32);
                f32x4 c0 = {0.f,0.f,0.f,0.f}, c1 = {0.f,0.f,0.f,0.f};
                __builtin_amdgcn_s_setprio(1);
                c0 = __builtin_amdgcn_mfma_f32_16x16x32_bf16(aw00, b0, c0, 0, 0, 0);
                c1 = __builtin_amdgcn_mfma_f32_16x16x32_bf16(aw10, b0, c1, 0, 0, 0);
                c0 = __builtin_amdgcn_mfma_f32_16x16x32_bf16(aw01, b1, c0, 0, 0, 0);
                c1 = __builtin_amdgcn_mfma_f32_16x16x32_bf16(aw11, b1, c1, 0, 0, 0);
                __builtin_amdgcn_s_setprio(0);
                int cb = i0 + t * 16 + lm + 1026 - cbeg;
                int base = i0 + 16 * t + 1026;
                if (base >= cbeg && base + 46 < cend) {
                    #pragma unroll
                    for (int r = 0; r < 4; ++r) {
                        int m0 = lq * 4 + r, m1 = m0 + 16;
                        sch[sidx(m0, cb + m0)] = __float2half(c0[r]);
                        sch[sidx(m1, cb + m1)] = __float2half(c1[r]);
                    }
                } else {
                    #pragma unroll
                    for (int r = 0; r < 4; ++r) {
                        int m0 = lq * 4 + r, m1 = m0 + 16;
                        int cA = cb + m0, cB = cb + m1;
                        if (cA >= 0 && cA < 1024) sch[sidx(m0, cA)] = __float2half(c0[r]);
                        if (cB >= 0 && cB < 1024) sch[sidx(m1, cB)] = __float2half(c1[r]);
                    }
                }
            }
        }

        // ---- prefetch first content K-tile before the barrier ----
        bf16x8 kb0, kb1;
        {
            int t0 = jh * 64 + w + 8 * (it & 7);
            const short* kp0 = kbase + (size_t)(t0 * 16 + lm) * DH + lq * 8;
            kb0 = *(const bf16x8*)kp0; kb1 = *(const bf16x8*)(kp0 + 32);
        }
        __syncthreads();

        // ---- Qu fragments ----
        const short* qup0 = qu_bf + ((size_t)(bh * S + i0 + lm)) * DH + lq * 8;
        const short* qup1 = qup0 + 16 * DH;
        bf16x8 au00 = *(const bf16x8*)qup0, au01 = *(const bf16x8*)(qup0 + 32);
        bf16x8 au10 = *(const bf16x8*)qup1, au11 = *(const bf16x8*)(qup1 + 32);

        // ---- content + softmax FUSED; depth-1 rolling K prefetch ----
        #pragma unroll 1
        for (int g = 0; g < 8; ++g) {
            bf16x8 nb0, nb1;
            if (g + 1 < 8) {
                int u = jh * 64 + w + 8 * ((g + 1 + it) & 7);
                const short* np = kbase + (size_t)(u * 16 + lm) * DH + lq * 8;
                nb0 = *(const bf16x8*)np; nb1 = *(const bf16x8*)(np + 32);
            }
            int t = jh * 64 + w + 8 * ((g + it) & 7);
            int lc = t * 16 - cbeg;                  // 16-aligned local col base
            int aA = sidx(lm,      lc + lq * 4);     // 4 consecutive u16, 8B-aligned
            int aB = sidx(lm + 16, lc + lq * 4);
            h16x4 hA = *(const h16x4*)(sc + aA);
            h16x4 hB = *(const h16x4*)(sc + aB);
            f32x4 c0, c1;
            #pragma unroll
            for (int r = 0; r < 4; ++r) { c0[r] = (float)hA[r]; c1[r] = (float)hB[r]; }
            __builtin_amdgcn_s_setprio(1);
            c0 = __builtin_amdgcn_mfma_f32_16x16x32_bf16(kb0, au00, c0, 0, 0, 0);
            c1 = __builtin_amdgcn_mfma_f32_16x16x32_bf16(kb0, au10, c1, 0, 0, 0);
            c0 = __builtin_amdgcn_mfma_f32_16x16x32_bf16(kb1, au01, c0, 0, 0, 0);
            c1 = __builtin_amdgcn_mfma_f32_16x16x32_bf16(kb1, au11, c1, 0, 0, 0);
            __builtin_amdgcn_s_setprio(0);
            us4 oA, oB;
            #pragma unroll
            for (int r = 0; r < 4; ++r) {
                float e0 = __builtin_amdgcn_exp2f(c0[r]);
                float e1 = __builtin_amdgcn_exp2f(c1[r]);
                sum0 += e0; sum1 += e1;
                oA[r] = f2bf_fast(e0);
                oB[r] = f2bf_fast(e1);
            }
            *(us4*)(sc + aA) = oA;
            *(us4*)(sc + aB) = oB;
            kb0 = nb0; kb1 = nb1;
        }

        // ---- prefetch first PV V-chunk before the barrier ----
        const short* vtb = vt_bf + ((size_t)bh * DH + dslice * 16 + lm) * J + cbeg + jq * 512;
        bf16x8 cv0, cv1, cv2, cv3;
        {
            int j0 = (it & 3) * 128;
            cv0 = *(const bf16x8*)(vtb + j0 +  0 + lq * 8);
            cv1 = *(const bf16x8*)(vtb + j0 + 32 + lq * 8);
            cv2 = *(const bf16x8*)(vtb + j0 + 64 + lq * 8);
            cv3 = *(const bf16x8*)(vtb + j0 + 96 + lq * 8);
        }
        __syncthreads();

        // ---- PV: wave -> d-slice (w&3), j-quarter (w>>2); accumulate ----
        #pragma unroll 1
        for (int jo0 = 0; jo0 < 4; ++jo0) {       // 128 local j per iteration
            bf16x8 nv0, nv1, nv2, nv3;
            if (jo0 < 3) {
                int jn = ((jo0 + 1 + it) & 3) * 128;
                nv0 = *(const bf16x8*)(vtb + jn +  0 + lq * 8);
                nv1 = *(const bf16x8*)(vtb + jn + 32 + lq * 8);
                nv2 = *(const bf16x8*)(vtb + jn + 64 + lq * 8);
                nv3 = *(const bf16x8*)(vtb + jn + 96 + lq * 8);
            }
            int j0 = ((jo0 + it) & 3) * 128;
            int lb = jq * 512 + j0;
            bf16x8 a0 = *(const bf16x8*)(sc + sidx(lm, lb +  0 + lq * 8));
            bf16x8 a1 = *(const bf16x8*)(sc + sidx(lm, lb + 32 + lq * 8));
            bf16x8 a2 = *(const bf16x8*)(sc + sidx(lm, lb + 64 + lq * 8));
            bf16x8 a3 = *(const bf16x8*)(sc + sidx(lm, lb + 96 + lq * 8));
            bf16x8 c0 = *(const bf16x8*)(sc + sidx(16 + lm, lb +  0 + lq * 8));
            bf16x8 c1 = *(const bf16x8*)(sc + sidx(16 + lm, lb + 32 + lq * 8));
            bf16x8 c2 = *(const bf16x8*)(sc + sidx(16 + lm, lb + 64 + lq * 8));
            bf16x8 c3 = *(const bf16x8*)(sc + sidx(16 + lm, lb + 96 + lq * 8));
            __builtin_amdgcn_s_setprio(1);
            pa0 = __builtin_amdgcn_mfma_f32_16x16x32_bf16(a0, cv0, pa0, 0, 0, 0);
            pb0 = __builtin_amdgcn_mfma_f32_16x16x32_bf16(c0, cv0, pb0, 0, 0, 0);
            pa1 = __builtin_amdgcn_mfma_f32_16x16x32_bf16(a1, cv1, pa1, 0, 0, 0);
            pb1 = __builtin_amdgcn_mfma_f32_16x16x32_bf16(c1, cv1, pb1, 0, 0, 0);
            pa2 = __builtin_amdgcn_mfma_f32_16x16x32_bf16(a2, cv2, pa2, 0, 0, 0);
            pb2 = __builtin_amdgcn_mfma_f32_16x16x32_bf16(c2, cv2, pb2, 0, 0, 0);
            pa3 = __builtin_amdgcn_mfma_f32_16x16x32_bf16(a3, cv3, pa3, 0, 0, 0);
            pb3 = __builtin_amdgcn_mfma_f32_16x16x32_bf16(c3, cv3, pb3, 0, 0, 0);
            __builtin_amdgcn_s_setprio(0);
            if (jo0 < 3) { cv0 = nv0; cv1 = nv1; cv2 = nv2; cv3 = nv3; }
        }
    }

    // ---- epilogue: row sums, O reduce, normalize, write o_bf ----
    sum0 += __shfl_xor(sum0, 16); sum0 += __shfl_xor(sum0, 32);
    sum1 += __shfl_xor(sum1, 16); sum1 += __shfl_xor(sum1, 32);
    if (lane < 16) { wsum[lane][0][w] = sum0; wsum[lane][1][w] = sum1; }
    __syncthreads();   // all PV score reads done; sc reusable; wsum visible

    #pragma unroll
    for (int r = 0; r < 4; ++r) {
        int m0 = lq * 4 + r, m1 = m0 + 16;
        scF[jq * 2048 + m0 * 64 + dslice * 16 + lm] = pa0[r] + pa1[r] + pa2[r] + pa3[r];
        scF[jq * 2048 + m1 * 64 + dslice * 16 + lm] = pb0[r] + pb1[r] + pb2[r] + pb3[r];
    }
    if (tid < 32) {
        float s = 0.f;
        #pragma unroll
        for (int ww = 0; ww < 8; ++ww) s += wsum[tid & 15][tid >> 4][ww];
        rtot[tid] = 1.0f / s;
    }
    __syncthreads();

    const int bb = bh >> 4;
    #pragma unroll
    for (int e = tid; e < 2048; e += 512) {
        int m = e >> 6, d = e & 63;
        float val = (scF[e] + scF[2048 + e]) * rtot[m];
        o_bf[((size_t)(i0 + m) * B + bb) * (H * DH) + h * DH + d] = f2bs(val);
    }
}

// ---------------------------------------------------------------------------
extern "C" void kernel_launch(void* const* d_in, const int* in_sizes, int n_in,
                              void* d_out, int out_size, void* d_ws, size_t ws_size,
                              hipStream_t stream)
{
    const float* x    = (const float*)d_in[0];   // [S, B, D]
    const float* pemb = (const float*)d_in[1];   // [S+M, D]
    const float* mem  = (const float*)d_in[2];   // [M, B, D]
    const float* u    = (const float*)d_in[3];   // [H, DH]
    const float* v    = (const float*)d_in[4];   // [H, DH]
    const float* Wkv  = (const float*)d_in[5];   // [D, 2*H*DH]
    const float* Wq   = (const float*)d_in[6];   // [D, H*DH]
    const float* Wpos = (const float*)d_in[7];   // [D, H*DH]
    const float* Wout = (const float*)d_in[8];   // [H*DH, D]
    float* out = (float*)d_out;                  // [S, B, D]

    char* p = (char*)d_ws;
    short* a_bf  = (short*)p; p += (size_t)4096 * 1024 * 2;    // mem||x  [0,8M)
    short* p_bf  = (short*)p; p += (size_t)2048 * 1024 * 2;    // [8M,12M)
    short* wkvt  = (short*)p; p += (size_t)2048 * 1024 * 2;    // [12M,16M)
    short* wqt   = (short*)p; p += (size_t)1024 * 1024 * 2;    // [16M,18M)
    short* wpt   = (short*)p; p += (size_t)1024 * 1024 * 2;    // [18M,20M)
    short* wot   = (short*)p; p += (size_t)1024 * 1024 * 2;    // [20M,22M)
    short* k_bf  = (short*)p; p += (size_t)B * H * J * DH * 2;
    short* vt_bf = (short*)p; p += (size_t)B * H * J * DH * 2;
    short* qu_bf = (short*)p; p += (size_t)B * H * S * DH * 2;
    short* qv_bf = (short*)p; p += (size_t)B * H * S * DH * 2;
    short* r_bf  = (short*)p; p += (size_t)H * J * DH * 2;
    short* o_bf  = (short*)p;

    prep<<<7424, 256, 0, stream>>>(mem, x, pemb, Wkv, Wq, Wpos, Wout,
                                   a_bf, p_bf, wkvt, wqt, wpt, wot);
    proj_fused<<<768, 256, 0, stream>>>(a_bf, p_bf, wkvt, wqt, wpt,
                                        k_bf, vt_bf, qu_bf, qv_bf, r_bf, u, v);
    attn_mfma<<<1024, 512, 0, stream>>>(
        qu_bf, qv_bf, k_bf, vt_bf, r_bf, o_bf);
    gemm_out<<<256, 256, 0, stream>>>(o_bf, wot, out);
}

// Round 16
// 273.223 us; speedup vs baseline: 1.1842x; 1.0172x over previous
//
#include <hip/hip_runtime.h>
#include <hip/hip_bf16.h>
#include <hip/hip_fp16.h>
#include <math.h>

#define D    1024
#define H    16
#define DH   64
#define S    1024
#define M    1024
#define B    2
#define J    2048          // M + S
#define SCALE 0.125f       // 1/sqrt(64)
#define SCALE_L2E 0.18033688f   // SCALE * log2(e): softmax uses bare exp2

typedef __attribute__((ext_vector_type(8))) short        bf16x8;
typedef __attribute__((ext_vector_type(4))) short        s16x4;
typedef __attribute__((ext_vector_type(8))) _Float16     h16x8;
typedef __attribute__((ext_vector_type(4))) _Float16     h16x4;
typedef __attribute__((ext_vector_type(8))) unsigned short us8;
typedef __attribute__((ext_vector_type(4))) unsigned short us4;
typedef __attribute__((ext_vector_type(4))) float        f32x4;

__device__ __forceinline__ short f2bs(float f) {
    __hip_bfloat16 t = __float2bfloat16(f);
    short r; __builtin_memcpy(&r, &t, 2); return r;
}
// fast bf16 pack (round-half-up); inputs finite non-negative (probs)
__device__ __forceinline__ unsigned short f2bf_fast(float f) {
    unsigned int u; __builtin_memcpy(&u, &f, 4);
    return (unsigned short)((u + 0x8000u) >> 16);
}

// async global->LDS, 16 bytes per lane
__device__ __forceinline__ void g2l16(const short* g, short* l) {
    __builtin_amdgcn_global_load_lds(
        (const __attribute__((address_space(1))) unsigned int*)g,
        (__attribute__((address_space(3))) unsigned int*)l, 16, 0, 0);
}

// ---------------------------------------------------------------------------
// prep: blocks [0,6144)  fp32->bf16 flat convert (mem||x -> a_bf, pemb -> p_bf)
//       blocks [6144,7424) 64x64 weight transpose+convert W[k][n] -> Wt[n][k]
// ---------------------------------------------------------------------------
__global__ __launch_bounds__(256)
void prep(const float* __restrict__ mem, const float* __restrict__ x,
          const float* __restrict__ pemb,
          const float* __restrict__ Wkv, const float* __restrict__ Wq,
          const float* __restrict__ Wpos, const float* __restrict__ Wout,
          short* __restrict__ a_bf, short* __restrict__ p_bf,
          short* __restrict__ wkvt, short* __restrict__ wqt,
          short* __restrict__ wpt,  short* __restrict__ wot)
{
    __shared__ float t[64][65];
    int blk = blockIdx.x;
    const int tid = threadIdx.x;
    if (blk < 6144) {
        const int idx = (blk * 256 + tid) * 4;
        const int TWO_M = 2 * 1024 * 1024;
        float4 v; short* dst;
        if (idx < TWO_M)          { v = *(const float4*)(mem  + idx);           dst = a_bf + idx; }
        else if (idx < 2 * TWO_M) { v = *(const float4*)(x    + idx - TWO_M);   dst = a_bf + idx; }
        else                      { v = *(const float4*)(pemb + idx - 2*TWO_M); dst = p_bf + idx - 2*TWO_M; }
        s16x4 o = { f2bs(v.x), f2bs(v.y), f2bs(v.z), f2bs(v.w) };
        *(s16x4*)dst = o;
        return;
    }
    blk -= 6144;
    const float* src; short* dst; int N, t0;
    if (blk < 512)       { src = Wkv;  dst = wkvt; N = 2048; t0 = blk; }
    else if (blk < 768)  { src = Wq;   dst = wqt;  N = 1024; t0 = blk - 512; }
    else if (blk < 1024) { src = Wpos; dst = wpt;  N = 1024; t0 = blk - 768; }
    else                 { src = Wout; dst = wot;  N = 1024; t0 = blk - 1024; }
    const int ntn = N >> 6;
    const int k0 = (t0 / ntn) * 64, n0 = (t0 % ntn) * 64;
    #pragma unroll
    for (int e = tid; e < 4096; e += 256) {
        int r = e >> 6, c = e & 63;
        t[r][c] = src[(size_t)(k0 + r) * N + n0 + c];
    }
    __syncthreads();
    #pragma unroll
    for (int e = tid; e < 4096; e += 256) {
        int nr = e >> 6, kc = e & 63;
        dst[(size_t)(n0 + nr) * 1024 + k0 + kc] = f2bs(t[kc][nr]);
    }
}

// ---------------------------------------------------------------------------
// Shared MFMA GEMM core: BM=BN=128, BK=64, 256 thr, K=1024.
// ---------------------------------------------------------------------------
__device__ __forceinline__ void gemm_core(const short* __restrict__ A,
                                          const short* __restrict__ Bt,
                                          short* As, short* Bs,
                                          int bm0, int bn0, int tid,
                                          f32x4 acc[4][4])
{
    const int w    = tid >> 6;
    const int wy   = w >> 1, wx = w & 1;
    const int lane = tid & 63;
    const int lm   = lane & 15;
    const int lq   = lane >> 4;

    for (int k0 = 0; k0 < 1024; k0 += 64) {
        const short* Ab = A  + (size_t)bm0 * 1024 + k0;
        const short* Bb = Bt + (size_t)bn0 * 1024 + k0;
        #pragma unroll
        for (int t = 0; t < 4; ++t) {
            int s = t * 256 + tid;
            int r = s >> 3, c = s & 7;
            int cg = c ^ (r & 7);
            g2l16(Ab + r * 1024 + cg * 8, As + s * 8);
            g2l16(Bb + r * 1024 + cg * 8, Bs + s * 8);
        }
        __syncthreads();
        #pragma unroll
        for (int kk = 0; kk < 2; ++kk) {
            bf16x8 af[4], bg[4];
            #pragma unroll
            for (int r4 = 0; r4 < 4; ++r4) {
                int ar = wy * 64 + r4 * 16 + lm;
                int kc = kk * 4 + lq;
                af[r4] = *(const bf16x8*)(As + ((ar << 3) + (kc ^ (ar & 7))) * 8);
            }
            #pragma unroll
            for (int c4 = 0; c4 < 4; ++c4) {
                int br = wx * 64 + c4 * 16 + lm;
                int kc = kk * 4 + lq;
                bg[c4] = *(const bf16x8*)(Bs + ((br << 3) + (kc ^ (br & 7))) * 8);
            }
            #pragma unroll
            for (int r4 = 0; r4 < 4; ++r4)
                #pragma unroll
                for (int c4 = 0; c4 < 4; ++c4)
                    acc[r4][c4] = __builtin_amdgcn_mfma_f32_16x16x32_bf16(
                        af[r4], bg[c4], acc[r4][c4], 0, 0, 0);
        }
        __syncthreads();
    }
}

// ---------------------------------------------------------------------------
// Fused kv/q/r projections. qu/qv scaled by SCALE*log2(e) (bare exp2 attn).
// XCD-aware block remap (bijective: 768 = 8 x 96).
// ---------------------------------------------------------------------------
__global__ __launch_bounds__(256)
void proj_fused(const short* __restrict__ a_bf, const short* __restrict__ p_bf,
                const short* __restrict__ wkvt, const short* __restrict__ wqt,
                const short* __restrict__ wpt,
                short* __restrict__ k_bf, short* __restrict__ vt_bf,
                short* __restrict__ qu_bf, short* __restrict__ qv_bf,
                short* __restrict__ r_bf,
                const float* __restrict__ uvec, const float* __restrict__ vvec)
{
    __shared__ __align__(16) short As[128 * 64];
    __shared__ __align__(16) short Bs[128 * 64];

    // XCD remap: HW sends original id L to XCD L&7; logical id below makes
    // XCD x execute the contiguous logical range [x*96, (x+1)*96).
    int blk = (blockIdx.x & 7) * 96 + (blockIdx.x >> 3);

    int mode, bx, by;
    const short *A, *Bt;
    if (blk < 512)      { bx = blk & 15; by = blk >> 4;
                          if (bx >= 8) { mode = 4; A = wkvt; Bt = a_bf; }   // swapped V
                          else         { mode = 0; A = a_bf; Bt = wkvt; } }
    else if (blk < 640) { int b2 = blk - 512; mode = 1; bx = b2 & 7; by = b2 >> 3;
                          A = a_bf + (size_t)2048 * 1024; Bt = wqt; }
    else                { int b3 = blk - 640; mode = 2; bx = b3 & 7; by = b3 >> 3;
                          A = p_bf; Bt = wpt; }
    const int bn0 = (mode == 4) ? by * 128 : bx * 128;
    const int bm0 = (mode == 4) ? bx * 128 : by * 128;
    const int tid = threadIdx.x;
    const int w = tid >> 6, wy = w >> 1, wx = w & 1;
    const int lane = tid & 63, lm = lane & 15, lq = lane >> 4;

    f32x4 acc[4][4];
    #pragma unroll
    for (int r = 0; r < 4; ++r)
        #pragma unroll
        for (int c = 0; c < 4; ++c) acc[r][c] = (f32x4){0.f, 0.f, 0.f, 0.f};

    gemm_core(A, Bt, As, Bs, bm0, bn0, tid, acc);

    #pragma unroll
    for (int r4 = 0; r4 < 4; ++r4) {
        #pragma unroll
        for (int c4 = 0; c4 < 4; ++c4) {
            const int n = bn0 + wx * 64 + c4 * 16 + lm;
            float ubias = 0.f, vbias = 0.f;
            if (mode == 1) { ubias = uvec[n]; vbias = vvec[n]; }
            #pragma unroll
            for (int reg = 0; reg < 4; ++reg) {
                const int m = bm0 + wy * 64 + r4 * 16 + lq * 4 + reg;
                const float val = acc[r4][c4][reg];
                if (mode == 0) {
                    int j = m >> 1, b = m & 1;
                    int h = n >> 6, d = n & 63;
                    k_bf[(((size_t)b * H + h) * J + j) * DH + d] = f2bs(val);
                } else if (mode == 4) {
                    int n2 = m - 1024, h = n2 >> 6, d = n2 & 63;
                    int j = n >> 1, b = n & 1;
                    vt_bf[(((size_t)b * H + h) * DH + d) * J + j] = f2bs(val);
                } else if (mode == 1) {
                    int i = m >> 1, b = m & 1;
                    int h = n >> 6, d = n & 63;
                    size_t o = (((size_t)b * H + h) * S + i) * DH + d;
                    qu_bf[o] = f2bs((val + ubias) * SCALE_L2E);
                    qv_bf[o] = f2bs((val + vbias) * SCALE_L2E);
                } else {
                    int h = n >> 6, d = n & 63;
                    r_bf[((size_t)h * J + m) * DH + d] = f2bs(val);
                }
            }
        }
    }
}

// ---------------------------------------------------------------------------
// Output projection: M=2048, N=1024, fp32 out. BM=64, BN=128, 256 blocks,
// XCD-contiguous logical order.
// ---------------------------------------------------------------------------
__global__ __launch_bounds__(256)
void gemm_out(const short* __restrict__ A, const short* __restrict__ Bt,
              float* __restrict__ out)
{
    __shared__ __align__(16) short As[64 * 64];    // 8 KB
    __shared__ __align__(16) short Bs[128 * 64];   // 16 KB
    const int lb = (blockIdx.x & 7) * 32 + (blockIdx.x >> 3);  // XCD-contig
    const int bn0 = (lb & 7) * 128, bm0 = (lb >> 3) * 64;
    const int tid = threadIdx.x;
    const int w = tid >> 6;                 // 0..3 = column-split wave index
    const int lane = tid & 63, lm = lane & 15, lq = lane >> 4;

    f32x4 acc[4][2];
    #pragma unroll
    for (int r = 0; r < 4; ++r)
        #pragma unroll
        for (int c = 0; c < 2; ++c) acc[r][c] = (f32x4){0.f, 0.f, 0.f, 0.f};

    for (int k0 = 0; k0 < 1024; k0 += 64) {
        const short* Ab = A  + (size_t)bm0 * 1024 + k0;
        const short* Bb = Bt + (size_t)bn0 * 1024 + k0;
        #pragma unroll
        for (int t = 0; t < 2; ++t) {       // A: 64 rows
            int s = t * 256 + tid;
            int r = s >> 3, c = s & 7;
            int cg = c ^ (r & 7);
            g2l16(Ab + r * 1024 + cg * 8, As + s * 8);
        }
        #pragma unroll
        for (int t = 0; t < 4; ++t) {       // B: 128 rows
            int s = t * 256 + tid;
            int r = s >> 3, c = s & 7;
            int cg = c ^ (r & 7);
            g2l16(Bb + r * 1024 + cg * 8, Bs + s * 8);
        }
        __syncthreads();
        #pragma unroll
        for (int kk = 0; kk < 2; ++kk) {
            bf16x8 af[4], bg[2];
            #pragma unroll
            for (int r4 = 0; r4 < 4; ++r4) {
                int ar = r4 * 16 + lm;
                int kc = kk * 4 + lq;
                af[r4] = *(const bf16x8*)(As + ((ar << 3) + (kc ^ (ar & 7))) * 8);
            }
            #pragma unroll
            for (int c4 = 0; c4 < 2; ++c4) {
                int br = w * 32 + c4 * 16 + lm;
                int kc = kk * 4 + lq;
                bg[c4] = *(const bf16x8*)(Bs + ((br << 3) + (kc ^ (br & 7))) * 8);
            }
            #pragma unroll
            for (int r4 = 0; r4 < 4; ++r4)
                #pragma unroll
                for (int c4 = 0; c4 < 2; ++c4)
                    acc[r4][c4] = __builtin_amdgcn_mfma_f32_16x16x32_bf16(
                        af[r4], bg[c4], acc[r4][c4], 0, 0, 0);
        }
        __syncthreads();
    }

    #pragma unroll
    for (int r4 = 0; r4 < 4; ++r4)
        #pragma unroll
        for (int c4 = 0; c4 < 2; ++c4) {
            const int n = bn0 + w * 32 + c4 * 16 + lm;
            #pragma unroll
            for (int reg = 0; reg < 4; ++reg) {
                const int m = bm0 + r4 * 16 + lq * 4 + reg;
                out[(size_t)m * 1024 + n] = acc[r4][c4][reg];
            }
        }
}

// ---------------------------------------------------------------------------
// MFMA attention — R26 = R21/R25 (the measured session optimum: fused jh
// loop, combine deleted, 118 us attn / 276-278 us total) + vectorized
// epilogue: the final o_bf loop was 4 scalar iterations/thread (8 scalar
// LDS reads + 4 x 2B stores); now one float4-pair read + one s16x4 store
// per thread (alignment: e = tid*4 is 4-aligned, same m within the quad;
// o_bf offset base = 0 mod 64 shorts + 4-aligned d -> 8B-aligned).
// Mapped landscape (kept for the record):
//  - 2 blocks/CU needs <=64 reported VGPR — unreachable for the fused
//    kernel; runs 1 block/CU and still beats split 2-block (117.6 vs
//    121.6 + combine kernel).
//  - Forced launch_bounds min-waves ALWAYS spills (R10/R15/R22).
//  - More waves in a monolithic barrier group is counterproductive (R12).
//  - Occupancy/LDS/latency/VALU levers neutral (R11-R19): bound by the
//    per-phase serial dependency structure.
// ---------------------------------------------------------------------------
__device__ __forceinline__ int sidx(int m, int c) {   // m in [0,32), c in [0,1024)
    return (m << 10) + (c ^ (m << 3));
}

__global__ __launch_bounds__(512)
void attn_mfma(const short* __restrict__ qu_bf, const short* __restrict__ qv_bf,
               const short* __restrict__ k_bf,  const short* __restrict__ vt_bf,
               const short* __restrict__ r_bf,
               short* __restrict__ o_bf)
{
    __shared__ unsigned short sc[32 * 1024];   // 64 KB
    __shared__ float wsum[16][2][8];           // per-wave row partials
    __shared__ float rtot[32];                 // final inverse row sums
    __half* sch = (__half*)sc;
    float*  scF = (float*)sc;                  // reused after PV reads

    // XCD-aware decode: L&7 = XCD; each XCD owns bh in [4*xcd, 4*xcd+4).
    const int L   = blockIdx.x;
    const int xcd = L & 7;
    const int pp  = L >> 3;                    // 0..127
    const int bh  = (xcd << 2) + (pp >> 5);    // 4 streams per XCD
    const int it  = pp & 31;

    const int i0  = it * 32;
    const int h   = bh & (H - 1);
    const int tid = threadIdx.x;
    const int w    = tid >> 6;       // 0..7
    const int lane = tid & 63;
    const int lm   = lane & 15;
    const int lq   = lane >> 4;
    const int dslice = w & 3, jq = w >> 2;

    const short* rbase = r_bf + (size_t)h * J * DH;
    const short* kbase = k_bf + (size_t)bh * J * DH;

    float sum0 = 0.f, sum1 = 0.f;
    f32x4 pa0 = {0.f,0.f,0.f,0.f}, pa1 = {0.f,0.f,0.f,0.f};
    f32x4 pa2 = {0.f,0.f,0.f,0.f}, pa3 = {0.f,0.f,0.f,0.f};
    f32x4 pb0 = {0.f,0.f,0.f,0.f}, pb1 = {0.f,0.f,0.f,0.f};
    f32x4 pb2 = {0.f,0.f,0.f,0.f}, pb3 = {0.f,0.f,0.f,0.f};

    #pragma unroll 1
    for (int jh = 0; jh < 2; ++jh) {
        const int cbeg = jh << 10, cend = cbeg + 1024;
        if (jh) __syncthreads();   // prev PV score reads done before overwrite

        // ---- Qv / Qw fragments (per iteration; short live ranges) ----
        const short* qvp0 = qv_bf + ((size_t)(bh * S + i0 + lm)) * DH + lq * 8;
        const short* qvp1 = qvp0 + 16 * DH;
        bf16x8 av00 = *(const bf16x8*)qvp0, av01 = *(const bf16x8*)(qvp0 + 32);
        bf16x8 av10 = *(const bf16x8*)qvp1, av11 = *(const bf16x8*)(qvp1 + 32);
        int r1a = i0 + 1 + lm;  if (r1a > S - 1) r1a = S - 1;   // clamped rows masked
        int r1b = i0 + 17 + lm; if (r1b > S - 1) r1b = S - 1;
        const short* qwp0 = qv_bf + ((size_t)(bh * S + r1a)) * DH + lq * 8;
        const short* qwp1 = qv_bf + ((size_t)(bh * S + r1b)) * DH + lq * 8;
        bf16x8 aw00 = *(const bf16x8*)qwp0, aw01 = *(const bf16x8*)(qwp0 + 32);
        bf16x8 aw10 = *(const bf16x8*)qwp1, aw11 = *(const bf16x8*)(qwp1 + 32);

        // ---- zero the pos hole column: row m, col i0+m+1025 (if in window) ----
        if (tid < 32) {
            int hole = i0 + tid + 1025;
            if (hole >= cbeg && hole < cend) sc[sidx(tid, hole - cbeg)] = 0;
        }

        // ---- pos main: col = i0 + 16t + lm + m - 1023; direct loads ----
        {
            int tmp = cbeg + 977 - i0;
            int tlo = tmp > 0 ? ((tmp + 15) >> 4) : 0;
            int thi = (cend + 1022 - i0) >> 4; if (thi > 127) thi = 127;
            for (int t = tlo + w; t <= thi; t += 8) {
                const short* rp = rbase + (size_t)(t * 16 + lm) * DH + lq * 8;
                bf16x8 b0 = *(const bf16x8*)rp, b1 = *(const bf16x8*)(rp + 32);
                f32x4 c0 = {0.f,0.f,0.f,0.f}, c1 = {0.f,0.f,0.f,0.f};
                __builtin_amdgcn_s_setprio(1);
                c0 = __builtin_amdgcn_mfma_f32_16x16x32_bf16(av00, b0, c0, 0, 0, 0);
                c1 = __builtin_amdgcn_mfma_f32_16x16x32_bf16(av10, b0, c1, 0, 0, 0);
                c0 = __builtin_amdgcn_mfma_f32_16x16x32_bf16(av01, b1, c0, 0, 0, 0);
                c1 = __builtin_amdgcn_mfma_f32_16x16x32_bf16(av11, b1, c1, 0, 0, 0);
                __builtin_amdgcn_s_setprio(0);
                int cb = i0 + t * 16 + lm - 1023 - cbeg;     // local col for m=0
                int base = i0 + 16 * t - 1023;               // scalar col_min
                if (base >= cbeg && base + 46 < cend) {
                    #pragma unroll
                    for (int r = 0; r < 4; ++r) {
                        int m0 = lq * 4 + r, m1 = m0 + 16;
                        sch[sidx(m0, cb + m0)] = __float2half(c0[r]);
                        sch[sidx(m1, cb + m1)] = __float2half(c1[r]);
                    }
                } else {
                    #pragma unroll
                    for (int r = 0; r < 4; ++r) {
                        int m0 = lq * 4 + r, m1 = m0 + 16;
                        int cA = cb + m0, cB = cb + m1;
                        if (cA >= 0 && cA < 1024) sch[sidx(m0, cA)] = __float2half(c0[r]);
                        if (cB >= 0 && cB < 1024) sch[sidx(m1, cB)] = __float2half(c1[r]);
                    }
                }
            }
        }

        // ---- pos wrap: col = i0 + 16t + lm + m + 1026, rows Qv[i+1] ----
        {
            int tmpw = cbeg - 1072 - i0;
            int tlw = tmpw > 0 ? ((tmpw + 15) >> 4) : 0;
            int thw = (cend - 1027 - i0) >> 4; if (thw > 127) thw = 127;
            for (int t = tlw + w; t <= thw; t += 8) {
                const short* rp = rbase + (size_t)(t * 16 + lm) * DH + lq * 8;
                bf16x8 b0 = *(const bf16x8*)rp, b1 = *(const bf16x8*)(rp + 32);
                f32x4 c0 = {0.f,0.f,0.f,0.f}, c1 = {0.f,0.f,0.f,0.f};
                __builtin_amdgcn_s_setprio(1);
                c0 = __builtin_amdgcn_mfma_f32_16x16x32_bf16(aw00, b0, c0, 0, 0, 0);
                c1 = __builtin_amdgcn_mfma_f32_16x16x32_bf16(aw10, b0, c1, 0, 0, 0);
                c0 = __builtin_amdgcn_mfma_f32_16x16x32_bf16(aw01, b1, c0, 0, 0, 0);
                c1 = __builtin_amdgcn_mfma_f32_16x16x32_bf16(aw11, b1, c1, 0, 0, 0);
                __builtin_amdgcn_s_setprio(0);
                int cb = i0 + t * 16 + lm + 1026 - cbeg;
                int base = i0 + 16 * t + 1026;
                if (base >= cbeg && base + 46 < cend) {
                    #pragma unroll
                    for (int r = 0; r < 4; ++r) {
                        int m0 = lq * 4 + r, m1 = m0 + 16;
                        sch[sidx(m0, cb + m0)] = __float2half(c0[r]);
                        sch[sidx(m1, cb + m1)] = __float2half(c1[r]);
                    }
                } else {
                    #pragma unroll
                    for (int r = 0; r < 4; ++r) {
                        int m0 = lq * 4 + r, m1 = m0 + 16;
                        int cA = cb + m0, cB = cb + m1;
                        if (cA >= 0 && cA < 1024) sch[sidx(m0, cA)] = __float2half(c0[r]);
                        if (cB >= 0 && cB < 1024) sch[sidx(m1, cB)] = __float2half(c1[r]);
                    }
                }
            }
        }

        // ---- prefetch first content K-tile before the barrier ----
        bf16x8 kb0, kb1;
        {
            int t0 = jh * 64 + w + 8 * (it & 7);
            const short* kp0 = kbase + (size_t)(t0 * 16 + lm) * DH + lq * 8;
            kb0 = *(const bf16x8*)kp0; kb1 = *(const bf16x8*)(kp0 + 32);
        }
        __syncthreads();

        // ---- Qu fragments ----
        const short* qup0 = qu_bf + ((size_t)(bh * S + i0 + lm)) * DH + lq * 8;
        const short* qup1 = qup0 + 16 * DH;
        bf16x8 au00 = *(const bf16x8*)qup0, au01 = *(const bf16x8*)(qup0 + 32);
        bf16x8 au10 = *(const bf16x8*)qup1, au11 = *(const bf16x8*)(qup1 + 32);

        // ---- content + softmax FUSED; depth-1 rolling K prefetch ----
        #pragma unroll 1
        for (int g = 0; g < 8; ++g) {
            bf16x8 nb0, nb1;
            if (g + 1 < 8) {
                int u = jh * 64 + w + 8 * ((g + 1 + it) & 7);
                const short* np = kbase + (size_t)(u * 16 + lm) * DH + lq * 8;
                nb0 = *(const bf16x8*)np; nb1 = *(const bf16x8*)(np + 32);
            }
            int t = jh * 64 + w + 8 * ((g + it) & 7);
            int lc = t * 16 - cbeg;                  // 16-aligned local col base
            int aA = sidx(lm,      lc + lq * 4);     // 4 consecutive u16, 8B-aligned
            int aB = sidx(lm + 16, lc + lq * 4);
            h16x4 hA = *(const h16x4*)(sc + aA);
            h16x4 hB = *(const h16x4*)(sc + aB);
            f32x4 c0, c1;
            #pragma unroll
            for (int r = 0; r < 4; ++r) { c0[r] = (float)hA[r]; c1[r] = (float)hB[r]; }
            __builtin_amdgcn_s_setprio(1);
            c0 = __builtin_amdgcn_mfma_f32_16x16x32_bf16(kb0, au00, c0, 0, 0, 0);
            c1 = __builtin_amdgcn_mfma_f32_16x16x32_bf16(kb0, au10, c1, 0, 0, 0);
            c0 = __builtin_amdgcn_mfma_f32_16x16x32_bf16(kb1, au01, c0, 0, 0, 0);
            c1 = __builtin_amdgcn_mfma_f32_16x16x32_bf16(kb1, au11, c1, 0, 0, 0);
            __builtin_amdgcn_s_setprio(0);
            us4 oA, oB;
            #pragma unroll
            for (int r = 0; r < 4; ++r) {
                float e0 = __builtin_amdgcn_exp2f(c0[r]);
                float e1 = __builtin_amdgcn_exp2f(c1[r]);
                sum0 += e0; sum1 += e1;
                oA[r] = f2bf_fast(e0);
                oB[r] = f2bf_fast(e1);
            }
            *(us4*)(sc + aA) = oA;
            *(us4*)(sc + aB) = oB;
            kb0 = nb0; kb1 = nb1;
        }

        // ---- prefetch first PV V-chunk before the barrier ----
        const short* vtb = vt_bf + ((size_t)bh * DH + dslice * 16 + lm) * J + cbeg + jq * 512;
        bf16x8 cv0, cv1, cv2, cv3;
        {
            int j0 = (it & 3) * 128;
            cv0 = *(const bf16x8*)(vtb + j0 +  0 + lq * 8);
            cv1 = *(const bf16x8*)(vtb + j0 + 32 + lq * 8);
            cv2 = *(const bf16x8*)(vtb + j0 + 64 + lq * 8);
            cv3 = *(const bf16x8*)(vtb + j0 + 96 + lq * 8);
        }
        __syncthreads();

        // ---- PV: wave -> d-slice (w&3), j-quarter (w>>2); accumulate ----
        #pragma unroll 1
        for (int jo0 = 0; jo0 < 4; ++jo0) {       // 128 local j per iteration
            bf16x8 nv0, nv1, nv2, nv3;
            if (jo0 < 3) {
                int jn = ((jo0 + 1 + it) & 3) * 128;
                nv0 = *(const bf16x8*)(vtb + jn +  0 + lq * 8);
                nv1 = *(const bf16x8*)(vtb + jn + 32 + lq * 8);
                nv2 = *(const bf16x8*)(vtb + jn + 64 + lq * 8);
                nv3 = *(const bf16x8*)(vtb + jn + 96 + lq * 8);
            }
            int j0 = ((jo0 + it) & 3) * 128;
            int lb = jq * 512 + j0;
            bf16x8 a0 = *(const bf16x8*)(sc + sidx(lm, lb +  0 + lq * 8));
            bf16x8 a1 = *(const bf16x8*)(sc + sidx(lm, lb + 32 + lq * 8));
            bf16x8 a2 = *(const bf16x8*)(sc + sidx(lm, lb + 64 + lq * 8));
            bf16x8 a3 = *(const bf16x8*)(sc + sidx(lm, lb + 96 + lq * 8));
            bf16x8 c0 = *(const bf16x8*)(sc + sidx(16 + lm, lb +  0 + lq * 8));
            bf16x8 c1 = *(const bf16x8*)(sc + sidx(16 + lm, lb + 32 + lq * 8));
            bf16x8 c2 = *(const bf16x8*)(sc + sidx(16 + lm, lb + 64 + lq * 8));
            bf16x8 c3 = *(const bf16x8*)(sc + sidx(16 + lm, lb + 96 + lq * 8));
            __builtin_amdgcn_s_setprio(1);
            pa0 = __builtin_amdgcn_mfma_f32_16x16x32_bf16(a0, cv0, pa0, 0, 0, 0);
            pb0 = __builtin_amdgcn_mfma_f32_16x16x32_bf16(c0, cv0, pb0, 0, 0, 0);
            pa1 = __builtin_amdgcn_mfma_f32_16x16x32_bf16(a1, cv1, pa1, 0, 0, 0);
            pb1 = __builtin_amdgcn_mfma_f32_16x16x32_bf16(c1, cv1, pb1, 0, 0, 0);
            pa2 = __builtin_amdgcn_mfma_f32_16x16x32_bf16(a2, cv2, pa2, 0, 0, 0);
            pb2 = __builtin_amdgcn_mfma_f32_16x16x32_bf16(c2, cv2, pb2, 0, 0, 0);
            pa3 = __builtin_amdgcn_mfma_f32_16x16x32_bf16(a3, cv3, pa3, 0, 0, 0);
            pb3 = __builtin_amdgcn_mfma_f32_16x16x32_bf16(c3, cv3, pb3, 0, 0, 0);
            __builtin_amdgcn_s_setprio(0);
            if (jo0 < 3) { cv0 = nv0; cv1 = nv1; cv2 = nv2; cv3 = nv3; }
        }
    }

    // ---- epilogue: row sums, O reduce, normalize, write o_bf ----
    sum0 += __shfl_xor(sum0, 16); sum0 += __shfl_xor(sum0, 32);
    sum1 += __shfl_xor(sum1, 16); sum1 += __shfl_xor(sum1, 32);
    if (lane < 16) { wsum[lane][0][w] = sum0; wsum[lane][1][w] = sum1; }
    __syncthreads();   // all PV score reads done; sc reusable; wsum visible

    #pragma unroll
    for (int r = 0; r < 4; ++r) {
        int m0 = lq * 4 + r, m1 = m0 + 16;
        scF[jq * 2048 + m0 * 64 + dslice * 16 + lm] = pa0[r] + pa1[r] + pa2[r] + pa3[r];
        scF[jq * 2048 + m1 * 64 + dslice * 16 + lm] = pb0[r] + pb1[r] + pb2[r] + pb3[r];
    }
    if (tid < 32) {
        float s = 0.f;
        #pragma unroll
        for (int ww = 0; ww < 8; ++ww) s += wsum[tid & 15][tid >> 4][ww];
        rtot[tid] = 1.0f / s;
    }
    __syncthreads();

    // vectorized final write: 4 consecutive elems per thread (same m)
    const int bb = bh >> 4;
    {
        int e = tid * 4;
        int m = e >> 6, d = e & 63;
        float4 a = *(const float4*)(scF + e);
        float4 b = *(const float4*)(scF + 2048 + e);
        float rt = rtot[m];
        s16x4 o = { f2bs((a.x + b.x) * rt), f2bs((a.y + b.y) * rt),
                    f2bs((a.z + b.z) * rt), f2bs((a.w + b.w) * rt) };
        *(s16x4*)(o_bf + ((size_t)(i0 + m) * B + bb) * (H * DH) + h * DH + d) = o;
    }
}

// ---------------------------------------------------------------------------
extern "C" void kernel_launch(void* const* d_in, const int* in_sizes, int n_in,
                              void* d_out, int out_size, void* d_ws, size_t ws_size,
                              hipStream_t stream)
{
    const float* x    = (const float*)d_in[0];   // [S, B, D]
    const float* pemb = (const float*)d_in[1];   // [S+M, D]
    const float* mem  = (const float*)d_in[2];   // [M, B, D]
    const float* u    = (const float*)d_in[3];   // [H, DH]
    const float* v    = (const float*)d_in[4];   // [H, DH]
    const float* Wkv  = (const float*)d_in[5];   // [D, 2*H*DH]
    const float* Wq   = (const float*)d_in[6];   // [D, H*DH]
    const float* Wpos = (const float*)d_in[7];   // [D, H*DH]
    const float* Wout = (const float*)d_in[8];   // [H*DH, D]
    float* out = (float*)d_out;                  // [S, B, D]

    char* p = (char*)d_ws;
    short* a_bf  = (short*)p; p += (size_t)4096 * 1024 * 2;    // mem||x  [0,8M)
    short* p_bf  = (short*)p; p += (size_t)2048 * 1024 * 2;    // [8M,12M)
    short* wkvt  = (short*)p; p += (size_t)2048 * 1024 * 2;    // [12M,16M)
    short* wqt   = (short*)p; p += (size_t)1024 * 1024 * 2;    // [16M,18M)
    short* wpt   = (short*)p; p += (size_t)1024 * 1024 * 2;    // [18M,20M)
    short* wot   = (short*)p; p += (size_t)1024 * 1024 * 2;    // [20M,22M)
    short* k_bf  = (short*)p; p += (size_t)B * H * J * DH * 2;
    short* vt_bf = (short*)p; p += (size_t)B * H * J * DH * 2;
    short* qu_bf = (short*)p; p += (size_t)B * H * S * DH * 2;
    short* qv_bf = (short*)p; p += (size_t)B * H * S * DH * 2;
    short* r_bf  = (short*)p; p += (size_t)H * J * DH * 2;
    short* o_bf  = (short*)p;

    prep<<<7424, 256, 0, stream>>>(mem, x, pemb, Wkv, Wq, Wpos, Wout,
                                   a_bf, p_bf, wkvt, wqt, wpt, wot);
    proj_fused<<<768, 256, 0, stream>>>(a_bf, p_bf, wkvt, wqt, wpt,
                                        k_bf, vt_bf, qu_bf, qv_bf, r_bf, u, v);
    attn_mfma<<<1024, 512, 0, stream>>>(
        qu_bf, qv_bf, k_bf, vt_bf, r_bf, o_bf);
    gemm_out<<<256, 256, 0, stream>>>(o_bf, wot, out);
}